// Round 9
// baseline (1609.615 us; speedup 1.0000x reference)
//
#include <hip/hip_runtime.h>
#include <math.h>

#define BB 256
#define NN 1023
#define FF 8
#define HH 256
#define DEPTH 9

enum { EPI_NONE = 0, EPI_SIGMUL = 1, EPI_RELU = 2, EPI_COMBINE = 3 };

typedef __bf16 bf16x8_t __attribute__((ext_vector_type(8)));
typedef float f32x4_t __attribute__((ext_vector_type(4)));

__device__ __forceinline__ void stage16(const void* g, void* l) {
    __builtin_amdgcn_global_load_lds(
        (const __attribute__((address_space(1))) void*)g,
        (__attribute__((address_space(3))) void*)l,
        16, 0, 0);
}

__device__ __forceinline__ int xcd_remap(int hw, int nwg) {
    const int xcd = hw & 7, k0 = hw >> 3;
    const int qq = nwg >> 3, rr = nwg & 7;
    return (xcd < rr ? xcd * (qq + 1) : rr * (qq + 1) + (xcd - rr) * qq) + k0;
}

// A-source for gather-staged GEMMs.
// SIGMUL K=576: [d(8)+pad56 | h_l 256 | h_r 256]
// COMBINE K=832: [h_new 256 | d(8)+pad56 | h_l 256 | h_r 256]
template <int EPI>
__device__ __forceinline__ const __bf16* a_src(
    int t, size_t gi, int l, int lrow, int scolz,
    const __bf16* __restrict__ hprev, const __bf16* __restrict__ hnew,
    const __bf16* __restrict__ dbf)
{
    const int b = (int)(gi >> l);
    const int m = (int)gi & ((1 << l) - 1);
    const size_t child = (((size_t)b) << (l + 1)) + 2 * m;
    if (EPI == EPI_SIGMUL) {
        if (t == 0) return dbf + ((size_t)b * NN + (1 << l) - 1 + m) * FF;
        if (t <= 4) return hprev + child * HH + (t - 1) * 64 + scolz;
        return hprev + (child + 1) * HH + (t - 5) * 64 + scolz;
    } else {
        if (t < 4) return hnew + (size_t)lrow * HH + t * 64 + scolz;
        if (t == 4) return dbf + ((size_t)b * NN + (1 << l) - 1 + m) * FF;
        if (t <= 8) return hprev + child * HH + (t - 5) * 64 + scolz;
        return hprev + (child + 1) * HH + (t - 9) * 64 + scolz;
    }
}

// ====== 256x256 tile, BK=64, gather-staged A, r7 counted-vmcnt K-loop ======
template <int EPI>
__global__ __launch_bounds__(512, 1) void gemm256g(
    const __bf16* __restrict__ hprev, const __bf16* __restrict__ ubuf,
    const __bf16* __restrict__ hnew, const __bf16* __restrict__ dbf,
    const __bf16* __restrict__ W,       // Nc x K row-major (folded)
    const float* __restrict__ bias,
    void* __restrict__ Cout,            // SIGMUL: rh (ldc 768); COMBINE: h global
    int r0, int l, int K)
{
    __shared__ __bf16 lds[2][2][256 * 64];
    const int tid = threadIdx.x;
    const int lane = tid & 63;
    const int w = tid >> 6;
    const int wr = w >> 2, wc = w & 3;

    const int nwg = gridDim.x * gridDim.y;
    const int hw = blockIdx.y * gridDim.x + blockIdx.x;
    const int wg = xcd_remap(hw, nwg);
    const int bm0 = (wg / gridDim.x) * 256;
    const int bn0 = (wg % gridDim.x) * 256;

    const int srow = tid >> 3;
    const int scolz = ((tid & 7) ^ (srow & 7)) * 8;
    const int mask = (1 << l) - 1;

    f32x4_t acc[8][4];
#pragma unroll
    for (int i = 0; i < 8; ++i)
#pragma unroll
        for (int j = 0; j < 4; ++j) acc[i][j] = (f32x4_t){0.f, 0.f, 0.f, 0.f};

    const int rA = lane & 15;
    const int klane = (lane >> 4) * 8;
    const int rxor = (lane & 7) * 8;
    const int NT = K >> 6;

#define STAGE_A_LINE(t, buf, rbase)                                            \
    do {                                                                       \
        const int lrow_ = bm0 + (rbase) + srow;                                \
        const __bf16* s_ = a_src<EPI>((t), (size_t)r0 + lrow_, l, lrow_,       \
                                      scolz, hprev, hnew, dbf);                \
        stage16(s_, &lds[buf][0][(rbase) * 64 + w * 512]);                     \
    } while (0)
#define STAGE_A_Q(t, buf, q)                                                   \
    do {                                                                       \
        STAGE_A_LINE(t, buf, (q) * 64);                                        \
        STAGE_A_LINE(t, buf, 128 + (q) * 64);                                  \
    } while (0)
#define STAGE_B_H(t, buf, hf)                                                  \
    do {                                                                       \
        const int kk_ = (t) << 6;                                              \
        stage16(W + (size_t)(bn0 + (hf) * 128 + srow) * K + kk_ + scolz,       \
                &lds[buf][1][((hf) * 128) * 64 + w * 512]);                    \
        stage16(W + (size_t)(bn0 + (hf) * 128 + 64 + srow) * K + kk_ + scolz,  \
                &lds[buf][1][((hf) * 128 + 64) * 64 + w * 512]);               \
    } while (0)
#define LDA_F(As_, i, ks) \
    (*(const bf16x8_t*)&(As_)[(wr * 128 + (i) * 16 + rA) * 64 + (((ks) * 32 + klane) ^ rxor)])
#define LDB_F(Bs_, j, ks) \
    (*(const bf16x8_t*)&(Bs_)[(wc * 64 + (j) * 16 + rA) * 64 + (((ks) * 32 + klane) ^ rxor)])

    STAGE_A_Q(0, 0, 0);
    STAGE_B_H(0, 0, 0);
    STAGE_B_H(0, 0, 1);
    STAGE_A_Q(0, 0, 1);
    asm volatile("s_waitcnt vmcnt(2)" ::: "memory");
    __builtin_amdgcn_s_barrier();

    for (int t = 0; t < NT; ++t) {
        const int c = t & 1, nb = c ^ 1;
        const __bf16* As = lds[c][0];
        const __bf16* Bs = lds[c][1];
        const bool more = (t + 1 < NT);
        bf16x8_t a0[4], a1[4], b0[4], b1[4];

        // phase 1: acc[0-3] x ks0
#pragma unroll
        for (int j = 0; j < 4; ++j) b0[j] = LDB_F(Bs, j, 0);
#pragma unroll
        for (int i = 0; i < 4; ++i) a0[i] = LDA_F(As, i, 0);
        if (more) STAGE_A_Q(t + 1, nb, 0);
        __builtin_amdgcn_s_barrier();
        asm volatile("s_waitcnt lgkmcnt(0)" ::: "memory");
        __builtin_amdgcn_s_setprio(1);
#pragma unroll
        for (int i = 0; i < 4; ++i)
#pragma unroll
            for (int j = 0; j < 4; ++j)
                acc[i][j] = __builtin_amdgcn_mfma_f32_16x16x32_bf16(
                    a0[i], b0[j], acc[i][j], 0, 0, 0);
        __builtin_amdgcn_s_setprio(0);
        __builtin_amdgcn_s_barrier();

        // phase 2: acc[0-3] x ks1
#pragma unroll
        for (int j = 0; j < 4; ++j) b1[j] = LDB_F(Bs, j, 1);
#pragma unroll
        for (int i = 0; i < 4; ++i) a1[i] = LDA_F(As, i, 1);
        if (more) STAGE_B_H(t + 1, nb, 0);
        __builtin_amdgcn_s_barrier();
        asm volatile("s_waitcnt lgkmcnt(0)" ::: "memory");
        __builtin_amdgcn_s_setprio(1);
#pragma unroll
        for (int i = 0; i < 4; ++i)
#pragma unroll
            for (int j = 0; j < 4; ++j)
                acc[i][j] = __builtin_amdgcn_mfma_f32_16x16x32_bf16(
                    a1[i], b1[j], acc[i][j], 0, 0, 0);
        __builtin_amdgcn_s_setprio(0);
        if (more) {
            asm volatile("s_waitcnt vmcnt(4)" ::: "memory");
        } else {
            asm volatile("s_waitcnt vmcnt(0)" ::: "memory");
        }
        __builtin_amdgcn_s_barrier();

        // phase 3: acc[4-7] x ks0
#pragma unroll
        for (int i = 0; i < 4; ++i) a0[i] = LDA_F(As, 4 + i, 0);
        if (more) STAGE_B_H(t + 1, nb, 1);
        __builtin_amdgcn_s_barrier();
        asm volatile("s_waitcnt lgkmcnt(0)" ::: "memory");
        __builtin_amdgcn_s_setprio(1);
#pragma unroll
        for (int i = 0; i < 4; ++i)
#pragma unroll
            for (int j = 0; j < 4; ++j)
                acc[4 + i][j] = __builtin_amdgcn_mfma_f32_16x16x32_bf16(
                    a0[i], b0[j], acc[4 + i][j], 0, 0, 0);
        __builtin_amdgcn_s_setprio(0);
        __builtin_amdgcn_s_barrier();

        // phase 4: acc[4-7] x ks1
#pragma unroll
        for (int i = 0; i < 4; ++i) a1[i] = LDA_F(As, 4 + i, 1);
        if (more) STAGE_A_Q(t + 1, nb, 1);
        __builtin_amdgcn_s_barrier();
        asm volatile("s_waitcnt lgkmcnt(0)" ::: "memory");
        __builtin_amdgcn_s_setprio(1);
#pragma unroll
        for (int i = 0; i < 4; ++i)
#pragma unroll
            for (int j = 0; j < 4; ++j)
                acc[4 + i][j] = __builtin_amdgcn_mfma_f32_16x16x32_bf16(
                    a1[i], b1[j], acc[4 + i][j], 0, 0, 0);
        __builtin_amdgcn_s_setprio(0);
        if (more) {
            asm volatile("s_waitcnt vmcnt(2)" ::: "memory");
            __builtin_amdgcn_s_barrier();
        }
    }
#undef STAGE_A_LINE
#undef STAGE_A_Q
#undef STAGE_B_H
#undef LDA_F
#undef LDB_F

    const int hi = lane >> 4;
    const int r = lane & 15;

    if (EPI == EPI_SIGMUL) {
#pragma unroll
        for (int j = 0; j < 4; ++j) {
            const int gc = bn0 + wc * 64 + j * 16 + r;
            const float bv = bias[gc];
#pragma unroll
            for (int i = 0; i < 8; ++i) {
#pragma unroll
                for (int reg = 0; reg < 4; ++reg) {
                    const int gr = bm0 + wr * 128 + i * 16 + hi * 4 + reg;
                    const size_t gi = (size_t)r0 + gr;
                    const int b = (int)(gi >> l);
                    const int m = (int)gi & mask;
                    const size_t child = (((size_t)b) << (l + 1)) + 2 * m;
                    float a;
                    if (gc < 256) a = (float)ubuf[(size_t)gr * HH + gc];
                    else if (gc < 512) a = (float)hprev[child * HH + gc - 256];
                    else a = (float)hprev[(child + 1) * HH + gc - 512];
                    float v = acc[i][j][reg] + bv;
                    float s = 1.0f / (1.0f + __expf(-v));
                    ((__bf16*)Cout)[(size_t)gr * 768 + gc] = (__bf16)(s * a);
                }
            }
        }
    } else {  // EPI_COMBINE
        const int G = ((bn0 + wc * 64) >> 2) + r;
        float bz4[4];
#pragma unroll
        for (int g = 0; g < 4; ++g) bz4[g] = bias[bn0 + wc * 64 + g * 16 + r];
#pragma unroll
        for (int i = 0; i < 8; ++i) {
#pragma unroll
            for (int reg = 0; reg < 4; ++reg) {
                const int gr = bm0 + wr * 128 + i * 16 + hi * 4 + reg;
                const size_t gi = (size_t)r0 + gr;
                const int b = (int)(gi >> l);
                const int m = (int)gi & mask;
                const size_t child = (((size_t)b) << (l + 1)) + 2 * m;
                float z0 = acc[i][0][reg] + bz4[0];
                float z1 = acc[i][1][reg] + bz4[1];
                float z2 = acc[i][2][reg] + bz4[2];
                float z3 = acc[i][3][reg] + bz4[3];
                float mx = fmaxf(fmaxf(z0, z1), fmaxf(z2, z3));
                float e0 = __expf(z0 - mx), e1 = __expf(z1 - mx);
                float e2 = __expf(z2 - mx), e3 = __expf(z3 - mx);
                float a0v = (float)hnew[(size_t)gr * HH + G];
                float a1v = (float)ubuf[(size_t)gr * HH + G];
                float a2v = (float)hprev[child * HH + G];
                float a3v = (float)hprev[(child + 1) * HH + G];
                float hv = (e0 * a0v + e1 * a1v + e2 * a2v + e3 * a3v) /
                           (e0 + e1 + e2 + e3);
                ((__bf16*)Cout)[gi * HH + G] = (__bf16)hv;
            }
        }
    }
}

// ---------------- 128x128-tile kernel (Wh + small levels, unchanged) --------
template <int EPI>
__global__ __launch_bounds__(256) void gemm_mfma(
    const __bf16* __restrict__ A, int lda,
    const __bf16* __restrict__ W,
    const float* __restrict__ bias,
    const __bf16* __restrict__ aux, int ldaux,
    void* __restrict__ Cout, int ldc,
    int K)
{
    __shared__ __bf16 As[128 * 32];
    __shared__ __bf16 Bs[128 * 32];
    const int tid = threadIdx.x;
    const int lane = tid & 63;
    const int w = tid >> 6;
    const int wr = w >> 1, wc = w & 1;

    const int nwg = gridDim.x * gridDim.y;
    const int hw = blockIdx.y * gridDim.x + blockIdx.x;
    const int wg = xcd_remap(hw, nwg);
    const int bm0 = (wg / gridDim.x) * 128;
    const int bn0 = (wg % gridDim.x) * 128;

    const int srow = lane >> 2;
    const int scol = (lane & 3) * 8;

    f32x4_t acc[4][4];
#pragma unroll
    for (int i = 0; i < 4; ++i)
#pragma unroll
        for (int j = 0; j < 4; ++j) acc[i][j] = (f32x4_t){0.f, 0.f, 0.f, 0.f};

    const int rA = lane & 15;
    const int kslot = (lane >> 4) * 8;

    for (int kk = 0; kk < K; kk += 32) {
        stage16(A + (size_t)(bm0 + w * 16 + srow) * lda + kk + scol,
                &As[(w * 16) * 32]);
        stage16(A + (size_t)(bm0 + 64 + w * 16 + srow) * lda + kk + scol,
                &As[(64 + w * 16) * 32]);
        stage16(W + (size_t)(bn0 + w * 16 + srow) * K + kk + scol,
                &Bs[(w * 16) * 32]);
        stage16(W + (size_t)(bn0 + 64 + w * 16 + srow) * K + kk + scol,
                &Bs[(64 + w * 16) * 32]);
        __syncthreads();

        bf16x8_t af[4], bfr[4];
#pragma unroll
        for (int i = 0; i < 4; ++i)
            af[i] = *(const bf16x8_t*)&As[(wr * 64 + i * 16 + rA) * 32 + kslot];
#pragma unroll
        for (int j = 0; j < 4; ++j)
            bfr[j] = *(const bf16x8_t*)&Bs[(wc * 64 + j * 16 + rA) * 32 + kslot];
#pragma unroll
        for (int i = 0; i < 4; ++i)
#pragma unroll
            for (int j = 0; j < 4; ++j)
                acc[i][j] = __builtin_amdgcn_mfma_f32_16x16x32_bf16(
                    af[i], bfr[j], acc[i][j], 0, 0, 0);
        __syncthreads();
    }

    if (EPI == EPI_COMBINE) {
        const int r = lane & 15;
        const int G = ((bn0 + wc * 64) >> 2) + r;
        float bz4[4];
#pragma unroll
        for (int g = 0; g < 4; ++g) bz4[g] = bias[bn0 + wc * 64 + g * 16 + r];
#pragma unroll
        for (int i = 0; i < 4; ++i) {
#pragma unroll
            for (int reg = 0; reg < 4; ++reg) {
                const int gr = bm0 + wr * 64 + i * 16 + (lane >> 4) * 4 + reg;
                float z0 = acc[i][0][reg] + bz4[0];
                float z1 = acc[i][1][reg] + bz4[1];
                float z2 = acc[i][2][reg] + bz4[2];
                float z3 = acc[i][3][reg] + bz4[3];
                float mx = fmaxf(fmaxf(z0, z1), fmaxf(z2, z3));
                float e0 = __expf(z0 - mx), e1 = __expf(z1 - mx);
                float e2 = __expf(z2 - mx), e3 = __expf(z3 - mx);
                const __bf16* hrow = aux + (size_t)gr * ldaux + G;
                float hv = (e0 * (float)hrow[0] + e1 * (float)hrow[256] +
                            e2 * (float)hrow[512] + e3 * (float)hrow[768]) /
                           (e0 + e1 + e2 + e3);
                ((__bf16*)Cout)[(size_t)gr * ldc + G] = (__bf16)hv;
            }
        }
    } else {
#pragma unroll
        for (int j = 0; j < 4; ++j) {
            const int gc = bn0 + wc * 64 + j * 16 + (lane & 15);
            const float bv = bias[gc];
#pragma unroll
            for (int i = 0; i < 4; ++i) {
#pragma unroll
                for (int reg = 0; reg < 4; ++reg) {
                    const int gr = bm0 + wr * 64 + i * 16 + (lane >> 4) * 4 + reg;
                    float v = acc[i][j][reg] + bv;
                    if (EPI == EPI_SIGMUL) {
                        float s = 1.0f / (1.0f + __expf(-v));
                        v = s * (float)aux[(size_t)gr * ldaux + gc];
                        ((__bf16*)Cout)[(size_t)gr * ldc + gc] = (__bf16)v;
                    } else if (EPI == EPI_RELU) {
                        v = fmaxf(v, 0.0f);
                        ((__bf16*)Cout)[(size_t)gr * ldc + gc] = (__bf16)v;
                    } else {
                        ((float*)Cout)[(size_t)gr * ldc + gc] = v;
                    }
                }
            }
        }
    }
}

// Old full-K weights (small-level path).
__global__ __launch_bounds__(256) void convert_weights(
    const float* __restrict__ Wr, const float* __restrict__ Wh,
    const float* __restrict__ Wz, const float* __restrict__ bz,
    __bf16* __restrict__ Wrb, __bf16* __restrict__ Whb,
    __bf16* __restrict__ Wzb, float* __restrict__ bzp)
{
    const int NR = 768 * 768, NH2 = 256 * 768, NZ = 1024 * 1024;
    const int idx0 = blockIdx.x * 256 + threadIdx.x;
    for (int i = idx0; i < NR + NH2 + NZ; i += gridDim.x * 256) {
        if (i < NR) Wrb[i] = (__bf16)Wr[i];
        else if (i < NR + NH2) Whb[i - NR] = (__bf16)Wh[i - NR];
        else {
            const int z = i - NR - NH2;
            const int p = z >> 10, k = z & 1023;
            const int o = ((p >> 4) & 3) * 256 + (p >> 6) * 16 + (p & 15);
            Wzb[z] = (__bf16)Wz[(size_t)o * 1024 + k];
        }
    }
    if (idx0 < 1024) {
        const int p = idx0;
        const int o = ((p >> 4) & 3) * 256 + (p >> 6) * 16 + (p & 15);
        bzp[p] = bz[o];
    }
}

__global__ __launch_bounds__(256) void conv_data(
    const float* __restrict__ data, __bf16* __restrict__ dbf)
{
    const int N = BB * NN * FF;
    for (int i = blockIdx.x * 256 + threadIdx.x; i < N; i += gridDim.x * 256)
        dbf[i] = (__bf16)data[i];
}

// Wr' = [Wr_u*Wu (8) | 0 (56) | Wr_l | Wr_r], br' = br + Wr_u*bu
__global__ __launch_bounds__(256) void fold_wr(
    const float* __restrict__ Wr, const float* __restrict__ Wu,
    const float* __restrict__ bu, const float* __restrict__ br,
    __bf16* __restrict__ Wrp, float* __restrict__ brp)
{
    const int j = blockIdx.x;
    const int c = threadIdx.x;
    __shared__ float red[256];
    const float wjc = Wr[(size_t)j * 768 + c];
    red[c] = wjc * bu[c];
    __syncthreads();
    for (int s = 128; s > 0; s >>= 1) { if (c < s) red[c] += red[c + s]; __syncthreads(); }
    if (c == 0) brp[j] = br[j] + red[0];
    for (int f = 0; f < 8; ++f) {
        __syncthreads();
        red[c] = wjc * Wu[c * 8 + f];
        __syncthreads();
        for (int s = 128; s > 0; s >>= 1) { if (c < s) red[c] += red[c + s]; __syncthreads(); }
        if (c == 0) Wrp[(size_t)j * 576 + f] = (__bf16)red[0];
    }
    if (c >= 8 && c < 64) Wrp[(size_t)j * 576 + c] = (__bf16)0.0f;
    Wrp[(size_t)j * 576 + 64 + c]  = (__bf16)Wr[(size_t)j * 768 + 256 + c];
    Wrp[(size_t)j * 576 + 320 + c] = (__bf16)Wr[(size_t)j * 768 + 512 + c];
}

// Wz' (row-permuted p->o) = [Wz_hnew | Wz_u*Wu (8) | 0 (56) | Wz_l | Wz_r]
__global__ __launch_bounds__(256) void fold_wz(
    const float* __restrict__ Wz, const float* __restrict__ Wu,
    const float* __restrict__ bu, const float* __restrict__ bz,
    __bf16* __restrict__ Wzp, float* __restrict__ bzpf)
{
    const int p = blockIdx.x;
    const int c = threadIdx.x;
    const int o = ((p >> 4) & 3) * 256 + (p >> 6) * 16 + (p & 15);
    __shared__ float red[256];
    const float wuc = Wz[(size_t)o * 1024 + 256 + c];
    red[c] = wuc * bu[c];
    __syncthreads();
    for (int s = 128; s > 0; s >>= 1) { if (c < s) red[c] += red[c + s]; __syncthreads(); }
    if (c == 0) bzpf[p] = bz[o] + red[0];
    for (int f = 0; f < 8; ++f) {
        __syncthreads();
        red[c] = wuc * Wu[c * 8 + f];
        __syncthreads();
        for (int s = 128; s > 0; s >>= 1) { if (c < s) red[c] += red[c + s]; __syncthreads(); }
        if (c == 0) Wzp[(size_t)p * 832 + 256 + f] = (__bf16)red[0];
    }
    if (c >= 8 && c < 64) Wzp[(size_t)p * 832 + 256 + c] = (__bf16)0.0f;
    Wzp[(size_t)p * 832 + c]       = (__bf16)Wz[(size_t)o * 1024 + c];
    Wzp[(size_t)p * 832 + 320 + c] = (__bf16)Wz[(size_t)o * 1024 + 512 + c];
    Wzp[(size_t)p * 832 + 576 + c] = (__bf16)Wz[(size_t)o * 1024 + 768 + c];
}

// u rows (node = (1<<l)-1 + m). out is pre-offset for global-row dispatches.
__global__ __launch_bounds__(256) void build_u(
    const float* __restrict__ data, const float* __restrict__ Wu,
    const float* __restrict__ bu, __bf16* __restrict__ out, int l, int r0)
{
    const int n = 1 << l;
    const int row = blockIdx.x * 8 + (threadIdx.x >> 5);
    const int c0 = (threadIdx.x & 31) * 8;
    const size_t i = (size_t)r0 + row;
    const int b = (int)(i >> l);
    const int m = (int)i & (n - 1);

    float wv[8][8];
#pragma unroll
    for (int cc = 0; cc < 8; ++cc) {
        float4 w0 = *(const float4*)&Wu[(c0 + cc) * 8];
        float4 w1 = *(const float4*)&Wu[(c0 + cc) * 8 + 4];
        wv[cc][0] = w0.x; wv[cc][1] = w0.y; wv[cc][2] = w0.z; wv[cc][3] = w0.w;
        wv[cc][4] = w1.x; wv[cc][5] = w1.y; wv[cc][6] = w1.z; wv[cc][7] = w1.w;
    }
    const float* dp = data + ((size_t)b * NN + (n - 1) + m) * FF;
    float4 d0 = *(const float4*)dp, d1 = *(const float4*)(dp + 4);
    float dv[8] = {d0.x, d0.y, d0.z, d0.w, d1.x, d1.y, d1.z, d1.w};
    bf16x8_t o;
#pragma unroll
    for (int cc = 0; cc < 8; ++cc) {
        float acc = bu[c0 + cc];
#pragma unroll
        for (int f = 0; f < 8; ++f) acc += dv[f] * wv[cc][f];
        o[cc] = (__bf16)acc;
    }
    *(bf16x8_t*)&out[(size_t)row * HH + c0] = o;
}

// Small-level hhhu builder (l<=2), unchanged semantics.
__global__ __launch_bounds__(256) void build_hhu(
    const float* __restrict__ data, const float* __restrict__ Wu,
    const float* __restrict__ bu, const __bf16* __restrict__ hprev,
    __bf16* __restrict__ hhhu, int l, int r0)
{
    const int n = 1 << l;
    const int row = blockIdx.x * 8 + (threadIdx.x >> 5);
    const int c0 = (threadIdx.x & 31) * 8;
    const int i = r0 + row;
    const int b = i >> l;
    const int m = i & (n - 1);

    float wv[8][8];
#pragma unroll
    for (int cc = 0; cc < 8; ++cc) {
        float4 w0 = *(const float4*)&Wu[(c0 + cc) * 8];
        float4 w1 = *(const float4*)&Wu[(c0 + cc) * 8 + 4];
        wv[cc][0] = w0.x; wv[cc][1] = w0.y; wv[cc][2] = w0.z; wv[cc][3] = w0.w;
        wv[cc][4] = w1.x; wv[cc][5] = w1.y; wv[cc][6] = w1.z; wv[cc][7] = w1.w;
    }
    const float* dp = data + ((size_t)b * NN + (n - 1) + m) * FF;
    float4 d0 = *(const float4*)dp, d1 = *(const float4*)(dp + 4);
    float dv[8] = {d0.x, d0.y, d0.z, d0.w, d1.x, d1.y, d1.z, d1.w};
    __bf16* rowp = hhhu + (size_t)row * 1024;
    bf16x8_t o;
#pragma unroll
    for (int cc = 0; cc < 8; ++cc) {
        float acc = bu[c0 + cc];
#pragma unroll
        for (int f = 0; f < 8; ++f) acc += dv[f] * wv[cc][f];
        o[cc] = (__bf16)acc;
    }
    *(bf16x8_t*)&rowp[256 + c0] = o;
    *(bf16x8_t*)&rowp[512 + c0] =
        *(const bf16x8_t*)&hprev[((size_t)b * (2 * n) + 2 * m) * HH + c0];
    *(bf16x8_t*)&rowp[768 + c0] =
        *(const bf16x8_t*)&hprev[((size_t)b * (2 * n) + 2 * m + 1) * HH + c0];
}

__global__ __launch_bounds__(256) void final_kernel(
    const __bf16* __restrict__ hfin, const float* __restrict__ Wp,
    const float* __restrict__ bp, float* __restrict__ out)
{
    const int b = blockIdx.x;
    const int t = threadIdx.x;
    __shared__ float red[256];
    red[t] = (float)hfin[(size_t)b * HH + t] * Wp[t];
    __syncthreads();
    for (int s = 128; s > 0; s >>= 1) {
        if (t < s) red[t] += red[t + s];
        __syncthreads();
    }
    if (t == 0) out[b] = red[0] + bp[0];
}

extern "C" void kernel_launch(void* const* d_in, const int* in_sizes, int n_in,
                              void* d_out, int out_size, void* d_ws, size_t ws_size,
                              hipStream_t stream)
{
    const float* data = (const float*)d_in[0];
    const float* Wu = (const float*)d_in[1];
    const float* bu = (const float*)d_in[2];
    const float* Wr = (const float*)d_in[3];
    const float* br = (const float*)d_in[4];
    const float* Wh = (const float*)d_in[5];
    const float* bh = (const float*)d_in[6];
    const float* Wz = (const float*)d_in[7];
    const float* bz = (const float*)d_in[8];
    const float* Wp = (const float*)d_in[9];
    const float* bp = (const float*)d_in[10];
    float* out = (float*)d_out;

    const size_t CAP = 32768;
    char* w = (char*)d_ws;
    __bf16* leafU = (__bf16*)w; w += (size_t)131072 * HH * 2;  // 67.1 MB
    __bf16* hA = (__bf16*)w;    w += (size_t)65536 * HH * 2;   // 33.6 MB
    __bf16* hB = (__bf16*)w;    w += (size_t)32768 * HH * 2;   // 16.8 MB
    __bf16* ubuf = (__bf16*)w;  w += CAP * HH * 2;             // 16.8 MB
    __bf16* hnewb = (__bf16*)w; w += CAP * HH * 2;             // 16.8 MB
    __bf16* rh = (__bf16*)w;    w += CAP * 768 * 2;            // 50.3 MB
    __bf16* dbf = (__bf16*)w;   w += (size_t)BB * NN * FF * 2; // 4.2 MB
    __bf16* hhhuS = (__bf16*)w; w += (size_t)1024 * 1024 * 2;  // 2.1 MB
    __bf16* Wrb = (__bf16*)w;   w += (size_t)768 * 768 * 2;
    __bf16* Whb = (__bf16*)w;   w += (size_t)256 * 768 * 2;
    __bf16* Wzb = (__bf16*)w;   w += (size_t)1024 * 1024 * 2;
    float* bzp = (float*)w;     w += 1024 * 4;
    __bf16* Wrp = (__bf16*)w;   w += (size_t)768 * 576 * 2;
    float* brp = (float*)w;     w += 768 * 4;
    __bf16* Wzp = (__bf16*)w;   w += (size_t)1024 * 832 * 2;
    float* bzpf = (float*)w;    w += 1024 * 4;

    convert_weights<<<2048, 256, 0, stream>>>(Wr, Wh, Wz, bz, Wrb, Whb, Wzb, bzp);
    conv_data<<<1024, 256, 0, stream>>>(data, dbf);
    fold_wr<<<768, 256, 0, stream>>>(Wr, Wu, bu, br, Wrp, brp);
    fold_wz<<<1024, 256, 0, stream>>>(Wz, Wu, bu, bz, Wzp, bzpf);
    build_u<<<131072 / 8, 256, 0, stream>>>(data, Wu, bu, leafU, 9, 0);  // leaves

    const __bf16* src = leafU;
    __bf16* dst = hA;
    __bf16* other = hB;
    for (int l = DEPTH - 1; l >= 3; --l) {
        const size_t M = (size_t)BB << l;
        for (size_t r0 = 0; r0 < M; r0 += CAP) {
            const int R = (int)((M - r0 < CAP) ? (M - r0) : CAP);
            build_u<<<R / 8, 256, 0, stream>>>(data, Wu, bu, ubuf, l, (int)r0);
            gemm256g<EPI_SIGMUL><<<dim3(3, R / 256), 512, 0, stream>>>(
                src, ubuf, nullptr, dbf, Wrp, brp, rh, (int)r0, l, 576);
            gemm_mfma<EPI_RELU><<<dim3(2, R / 128), 256, 0, stream>>>(
                rh, 768, Whb, bh, nullptr, 0, hnewb, 256, 768);
            gemm256g<EPI_COMBINE><<<dim3(4, R / 256), 512, 0, stream>>>(
                src, ubuf, hnewb, dbf, Wzp, bzpf, dst, (int)r0, l, 832);
        }
        src = dst;
        __bf16* t2 = dst; dst = other; other = t2;
    }
    for (int l = 2; l >= 0; --l) {
        const int R = BB << l;
        build_hhu<<<R / 8, 256, 0, stream>>>(data, Wu, bu, src, hhhuS, l, 0);
        gemm_mfma<EPI_SIGMUL><<<dim3(6, R / 128), 256, 0, stream>>>(
            hhhuS + 256, 1024, Wrb, br, hhhuS + 256, 1024, rh, 768, 768);
        gemm_mfma<EPI_RELU><<<dim3(2, R / 128), 256, 0, stream>>>(
            rh, 768, Whb, bh, nullptr, 0, hhhuS, 1024, 768);
        gemm_mfma<EPI_COMBINE><<<dim3(8, R / 128), 256, 0, stream>>>(
            hhhuS, 1024, Wzb, bzp, hhhuS, 1024, dst, HH, 1024);
        src = dst;
        __bf16* t2 = dst; dst = other; other = t2;
    }
    final_kernel<<<BB, 256, 0, stream>>>(src, Wp, bp, out);
}

// Round 10
// 1228.372 us; speedup vs baseline: 1.3104x; 1.3104x over previous
//
#include <hip/hip_runtime.h>
#include <math.h>

#define BB 256
#define NN 1023
#define FF 8
#define HH 256
#define DEPTH 9

enum { EPI_NONE = 0, EPI_SIGMUL = 1, EPI_RELU = 2, EPI_COMBINE = 3 };

typedef __bf16 bf16x8_t __attribute__((ext_vector_type(8)));
typedef float f32x4_t __attribute__((ext_vector_type(4)));

__device__ __forceinline__ void stage16(const void* g, void* l) {
    __builtin_amdgcn_global_load_lds(
        (const __attribute__((address_space(1))) void*)g,
        (__attribute__((address_space(3))) void*)l,
        16, 0, 0);
}

__device__ __forceinline__ int xcd_remap(int hw, int nwg) {
    const int xcd = hw & 7, k0 = hw >> 3;
    const int qq = nwg >> 3, rr = nwg & 7;
    return (xcd < rr ? xcd * (qq + 1) : rr * (qq + 1) + (xcd - rr) * qq) + k0;
}

// ======== 256x256 tile, BK=64, 16 waves (64x64 C each), counted vmcnt =======
// Round-5 ledger, but 1024 threads: 4 waves/SIMD so MFMA-phase waves overlap
// staging/barrier waits of others (m114 mechanism). acc[4][4]=64 AGPR/wave.
template <int EPI>
__global__ __launch_bounds__(1024, 4) void gemm256w(
    const __bf16* __restrict__ A, int lda,
    const __bf16* __restrict__ W,       // Nc x K row-major
    const float* __restrict__ bias,
    const __bf16* __restrict__ aux, int ldaux,
    void* __restrict__ Cout, int ldc,
    int K)
{
    __shared__ __bf16 lds[2][2][256 * 64];  // 128 KiB
    const int tid = threadIdx.x;
    const int lane = tid & 63;
    const int w = tid >> 6;            // 0..15
    const int wr = w >> 2, wc = w & 3; // per-wave C = 64x64

    const int nwg = gridDim.x * gridDim.y;
    const int hw = blockIdx.y * gridDim.x + blockIdx.x;
    const int wg = xcd_remap(hw, nwg);
    const int bm0 = (wg / gridDim.x) * 256;
    const int bn0 = (wg % gridDim.x) * 256;

    const int srow = tid >> 3;                       // 0..127
    const int scolz = ((tid & 7) ^ (srow & 7)) * 8;  // inv-swizzled col

    f32x4_t acc[4][4];
#pragma unroll
    for (int i = 0; i < 4; ++i)
#pragma unroll
        for (int j = 0; j < 4; ++j) acc[i][j] = (f32x4_t){0.f, 0.f, 0.f, 0.f};

    const int rA = lane & 15;
    const int klane = (lane >> 4) * 8;
    const int rxor = (lane & 7) * 8;
    const int NT = K >> 6;

    // 4 stage ops per K-tile; each op = 1024 thr x 16B = 128 rows.
#define STAGE_T(t, buf)                                                        \
    do {                                                                       \
        const int kk_ = (t) << 6;                                              \
        stage16(A + (size_t)(bm0 + srow) * lda + kk_ + scolz,                  \
                &lds[buf][0][w * 512]);                                        \
        stage16(A + (size_t)(bm0 + 128 + srow) * lda + kk_ + scolz,            \
                &lds[buf][0][8192 + w * 512]);                                 \
        stage16(W + (size_t)(bn0 + srow) * K + kk_ + scolz,                    \
                &lds[buf][1][w * 512]);                                        \
        stage16(W + (size_t)(bn0 + 128 + srow) * K + kk_ + scolz,              \
                &lds[buf][1][8192 + w * 512]);                                 \
    } while (0)
#define LDA_F(As_, i, ks) \
    (*(const bf16x8_t*)&(As_)[(wr * 64 + (i) * 16 + rA) * 64 + (((ks) * 32 + klane) ^ rxor)])
#define LDB_F(Bs_, j, ks) \
    (*(const bf16x8_t*)&(Bs_)[(wc * 64 + (j) * 16 + rA) * 64 + (((ks) * 32 + klane) ^ rxor)])

    // prologue: stage tiles 0,1; wait tile 0 (4 newest in flight).
    STAGE_T(0, 0);
    STAGE_T(1, 1);
    asm volatile("s_waitcnt vmcnt(4)" ::: "memory");
    __builtin_amdgcn_s_barrier();

    for (int t = 0; t < NT; ++t) {
        const int cur = t & 1;
        const __bf16* As = lds[cur][0];
        const __bf16* Bs = lds[cur][1];
        bf16x8_t af[4], bf[4];

        // ks = 0: read + all 16 MFMAs
#pragma unroll
        for (int j = 0; j < 4; ++j) bf[j] = LDB_F(Bs, j, 0);
#pragma unroll
        for (int i = 0; i < 4; ++i) af[i] = LDA_F(As, i, 0);
#pragma unroll
        for (int i = 0; i < 4; ++i)
#pragma unroll
            for (int j = 0; j < 4; ++j)
                acc[i][j] = __builtin_amdgcn_mfma_f32_16x16x32_bf16(
                    af[i], bf[j], acc[i][j], 0, 0, 0);
        // ks = 1: read, half MFMAs
#pragma unroll
        for (int j = 0; j < 4; ++j) bf[j] = LDB_F(Bs, j, 1);
#pragma unroll
        for (int i = 0; i < 4; ++i) af[i] = LDA_F(As, i, 1);
#pragma unroll
        for (int i = 0; i < 2; ++i)
#pragma unroll
            for (int j = 0; j < 4; ++j)
                acc[i][j] = __builtin_amdgcn_mfma_f32_16x16x32_bf16(
                    af[i], bf[j], acc[i][j], 0, 0, 0);

        // all ds_reads of buf cur done (drain) -> barrier -> safe to restage
        asm volatile("s_waitcnt lgkmcnt(0)" ::: "memory");
        __builtin_amdgcn_s_barrier();
        if (t + 2 < NT) STAGE_T(t + 2, cur);

        __builtin_amdgcn_s_setprio(1);
#pragma unroll
        for (int i = 2; i < 4; ++i)
#pragma unroll
            for (int j = 0; j < 4; ++j)
                acc[i][j] = __builtin_amdgcn_mfma_f32_16x16x32_bf16(
                    af[i], bf[j], acc[i][j], 0, 0, 0);
        __builtin_amdgcn_s_setprio(0);

        if (t + 1 < NT) {
            if (t + 2 < NT) {
                asm volatile("s_waitcnt vmcnt(4)" ::: "memory");  // t+1 landed
            } else {
                asm volatile("s_waitcnt vmcnt(0)" ::: "memory");
            }
            __builtin_amdgcn_s_barrier();
        }
    }
#undef STAGE_T
#undef LDA_F
#undef LDB_F

    const int hi = lane >> 4;
    const int r = lane & 15;

    if (EPI == EPI_COMBINE) {
        const int G = ((bn0 + wc * 64) >> 2) + r;
        float bz4[4];
#pragma unroll
        for (int g = 0; g < 4; ++g) bz4[g] = bias[bn0 + wc * 64 + g * 16 + r];
#pragma unroll
        for (int i = 0; i < 4; ++i) {
#pragma unroll
            for (int reg = 0; reg < 4; ++reg) {
                const int gr = bm0 + wr * 64 + i * 16 + hi * 4 + reg;
                float z0 = acc[i][0][reg] + bz4[0];
                float z1 = acc[i][1][reg] + bz4[1];
                float z2 = acc[i][2][reg] + bz4[2];
                float z3 = acc[i][3][reg] + bz4[3];
                float mx = fmaxf(fmaxf(z0, z1), fmaxf(z2, z3));
                float e0 = __expf(z0 - mx), e1 = __expf(z1 - mx);
                float e2 = __expf(z2 - mx), e3 = __expf(z3 - mx);
                const __bf16* hrow = aux + (size_t)gr * ldaux + G;
                float hv = (e0 * (float)hrow[0] + e1 * (float)hrow[256] +
                            e2 * (float)hrow[512] + e3 * (float)hrow[768]) /
                           (e0 + e1 + e2 + e3);
                ((__bf16*)Cout)[(size_t)gr * ldc + G] = (__bf16)hv;
            }
        }
    } else {
#pragma unroll
        for (int j = 0; j < 4; ++j) {
            const int gc = bn0 + wc * 64 + j * 16 + r;
            const float bv = bias[gc];
#pragma unroll
            for (int i = 0; i < 4; ++i) {
#pragma unroll
                for (int reg = 0; reg < 4; ++reg) {
                    const int gr = bm0 + wr * 64 + i * 16 + hi * 4 + reg;
                    float v = acc[i][j][reg] + bv;
                    if (EPI == EPI_SIGMUL) {
                        float s = 1.0f / (1.0f + __expf(-v));
                        v = s * (float)aux[(size_t)gr * ldaux + gc];
                        ((__bf16*)Cout)[(size_t)gr * ldc + gc] = (__bf16)v;
                    } else if (EPI == EPI_RELU) {
                        v = fmaxf(v, 0.0f);
                        ((__bf16*)Cout)[(size_t)gr * ldc + gc] = (__bf16)v;
                    } else {
                        ((float*)Cout)[(size_t)gr * ldc + gc] = v;
                    }
                }
            }
        }
    }
}

// ---------------- 128x128-tile kernel (proven; Wh + small levels) -----------
template <int EPI>
__global__ __launch_bounds__(256) void gemm_mfma(
    const __bf16* __restrict__ A, int lda,
    const __bf16* __restrict__ W,
    const float* __restrict__ bias,
    const __bf16* __restrict__ aux, int ldaux,
    void* __restrict__ Cout, int ldc,
    int K)
{
    __shared__ __bf16 As[128 * 32];
    __shared__ __bf16 Bs[128 * 32];
    const int tid = threadIdx.x;
    const int lane = tid & 63;
    const int w = tid >> 6;
    const int wr = w >> 1, wc = w & 1;

    const int nwg = gridDim.x * gridDim.y;
    const int hw = blockIdx.y * gridDim.x + blockIdx.x;
    const int wg = xcd_remap(hw, nwg);
    const int bm0 = (wg / gridDim.x) * 128;
    const int bn0 = (wg % gridDim.x) * 128;

    const int srow = lane >> 2;
    const int scol = (lane & 3) * 8;

    f32x4_t acc[4][4];
#pragma unroll
    for (int i = 0; i < 4; ++i)
#pragma unroll
        for (int j = 0; j < 4; ++j) acc[i][j] = (f32x4_t){0.f, 0.f, 0.f, 0.f};

    const int rA = lane & 15;
    const int kslot = (lane >> 4) * 8;

    for (int kk = 0; kk < K; kk += 32) {
        stage16(A + (size_t)(bm0 + w * 16 + srow) * lda + kk + scol,
                &As[(w * 16) * 32]);
        stage16(A + (size_t)(bm0 + 64 + w * 16 + srow) * lda + kk + scol,
                &As[(64 + w * 16) * 32]);
        stage16(W + (size_t)(bn0 + w * 16 + srow) * K + kk + scol,
                &Bs[(w * 16) * 32]);
        stage16(W + (size_t)(bn0 + 64 + w * 16 + srow) * K + kk + scol,
                &Bs[(64 + w * 16) * 32]);
        __syncthreads();

        bf16x8_t af[4], bfr[4];
#pragma unroll
        for (int i = 0; i < 4; ++i)
            af[i] = *(const bf16x8_t*)&As[(wr * 64 + i * 16 + rA) * 32 + kslot];
#pragma unroll
        for (int j = 0; j < 4; ++j)
            bfr[j] = *(const bf16x8_t*)&Bs[(wc * 64 + j * 16 + rA) * 32 + kslot];
#pragma unroll
        for (int i = 0; i < 4; ++i)
#pragma unroll
            for (int j = 0; j < 4; ++j)
                acc[i][j] = __builtin_amdgcn_mfma_f32_16x16x32_bf16(
                    af[i], bfr[j], acc[i][j], 0, 0, 0);
        __syncthreads();
    }

    if (EPI == EPI_COMBINE) {
        const int r = lane & 15;
        const int G = ((bn0 + wc * 64) >> 2) + r;
        float bz4[4];
#pragma unroll
        for (int g = 0; g < 4; ++g) bz4[g] = bias[bn0 + wc * 64 + g * 16 + r];
#pragma unroll
        for (int i = 0; i < 4; ++i) {
#pragma unroll
            for (int reg = 0; reg < 4; ++reg) {
                const int gr = bm0 + wr * 64 + i * 16 + (lane >> 4) * 4 + reg;
                float z0 = acc[i][0][reg] + bz4[0];
                float z1 = acc[i][1][reg] + bz4[1];
                float z2 = acc[i][2][reg] + bz4[2];
                float z3 = acc[i][3][reg] + bz4[3];
                float mx = fmaxf(fmaxf(z0, z1), fmaxf(z2, z3));
                float e0 = __expf(z0 - mx), e1 = __expf(z1 - mx);
                float e2 = __expf(z2 - mx), e3 = __expf(z3 - mx);
                const __bf16* hrow = aux + (size_t)gr * ldaux + G;
                float hv = (e0 * (float)hrow[0] + e1 * (float)hrow[256] +
                            e2 * (float)hrow[512] + e3 * (float)hrow[768]) /
                           (e0 + e1 + e2 + e3);
                ((__bf16*)Cout)[(size_t)gr * ldc + G] = (__bf16)hv;
            }
        }
    } else {
#pragma unroll
        for (int j = 0; j < 4; ++j) {
            const int gc = bn0 + wc * 64 + j * 16 + (lane & 15);
            const float bv = bias[gc];
#pragma unroll
            for (int i = 0; i < 4; ++i) {
#pragma unroll
                for (int reg = 0; reg < 4; ++reg) {
                    const int gr = bm0 + wr * 64 + i * 16 + (lane >> 4) * 4 + reg;
                    float v = acc[i][j][reg] + bv;
                    if (EPI == EPI_SIGMUL) {
                        float s = 1.0f / (1.0f + __expf(-v));
                        v = s * (float)aux[(size_t)gr * ldaux + gc];
                        ((__bf16*)Cout)[(size_t)gr * ldc + gc] = (__bf16)v;
                    } else if (EPI == EPI_RELU) {
                        v = fmaxf(v, 0.0f);
                        ((__bf16*)Cout)[(size_t)gr * ldc + gc] = (__bf16)v;
                    } else {
                        ((float*)Cout)[(size_t)gr * ldc + gc] = v;
                    }
                }
            }
        }
    }
}

// Wr/Wh -> bf16; Wz -> bf16 with softmax-group row permutation.
__global__ __launch_bounds__(256) void convert_weights(
    const float* __restrict__ Wr, const float* __restrict__ Wh,
    const float* __restrict__ Wz, const float* __restrict__ bz,
    __bf16* __restrict__ Wrb, __bf16* __restrict__ Whb,
    __bf16* __restrict__ Wzb, float* __restrict__ bzp)
{
    const int NR = 768 * 768, NH2 = 256 * 768, NZ = 1024 * 1024;
    const int idx0 = blockIdx.x * 256 + threadIdx.x;
    for (int i = idx0; i < NR + NH2 + NZ; i += gridDim.x * 256) {
        if (i < NR) Wrb[i] = (__bf16)Wr[i];
        else if (i < NR + NH2) Whb[i - NR] = (__bf16)Wh[i - NR];
        else {
            const int z = i - NR - NH2;
            const int p = z >> 10, k = z & 1023;
            const int o = ((p >> 4) & 3) * 256 + (p >> 6) * 16 + (p & 15);
            Wzb[z] = (__bf16)Wz[(size_t)o * 1024 + k];
        }
    }
    if (idx0 < 1024) {
        const int p = idx0;
        const int o = ((p >> 4) & 3) * 256 + (p >> 6) * 16 + (p & 15);
        bzp[p] = bz[o];
    }
}

// hhhu cols 256..1024 = [parent_u, h_l, h_r]; 8 rows/block, 8 cols/thread.
__global__ __launch_bounds__(256) void build_hhu(
    const float* __restrict__ data, const float* __restrict__ Wu,
    const float* __restrict__ bu, const __bf16* __restrict__ hprev,
    __bf16* __restrict__ hhhu, int l, int r0)
{
    const int n = 1 << l;
    const int blk = xcd_remap(blockIdx.x, gridDim.x);
    const int row = blk * 8 + (threadIdx.x >> 5);
    const int c0 = (threadIdx.x & 31) * 8;
    const int i = r0 + row;
    const int b = i >> l;
    const int m = i & (n - 1);

    float wv[8][8];
#pragma unroll
    for (int cc = 0; cc < 8; ++cc) {
        float4 w0 = *(const float4*)&Wu[(c0 + cc) * 8];
        float4 w1 = *(const float4*)&Wu[(c0 + cc) * 8 + 4];
        wv[cc][0] = w0.x; wv[cc][1] = w0.y; wv[cc][2] = w0.z; wv[cc][3] = w0.w;
        wv[cc][4] = w1.x; wv[cc][5] = w1.y; wv[cc][6] = w1.z; wv[cc][7] = w1.w;
    }
    float buv[8];
#pragma unroll
    for (int cc = 0; cc < 8; ++cc) buv[cc] = bu[c0 + cc];

    __bf16* rowp = hhhu + (size_t)row * 1024;

    {
        const float* dp = data + ((size_t)b * NN + (n - 1) + m) * FF;
        float4 d0 = *(const float4*)dp, d1 = *(const float4*)(dp + 4);
        float dv[8] = {d0.x, d0.y, d0.z, d0.w, d1.x, d1.y, d1.z, d1.w};
        bf16x8_t o;
#pragma unroll
        for (int cc = 0; cc < 8; ++cc) {
            float acc = buv[cc];
#pragma unroll
            for (int f = 0; f < 8; ++f) acc += dv[f] * wv[cc][f];
            o[cc] = (__bf16)acc;
        }
        *(bf16x8_t*)&rowp[256 + c0] = o;
    }

    if (l == 8) {
        const float* dl = data + ((size_t)b * NN + 511 + 2 * m) * FF;
#pragma unroll
        for (int side = 0; side < 2; ++side) {
            const float* dp = dl + side * FF;
            float4 d0 = *(const float4*)dp, d1 = *(const float4*)(dp + 4);
            float dv[8] = {d0.x, d0.y, d0.z, d0.w, d1.x, d1.y, d1.z, d1.w};
            bf16x8_t o;
#pragma unroll
            for (int cc = 0; cc < 8; ++cc) {
                float acc = buv[cc];
#pragma unroll
                for (int f = 0; f < 8; ++f) acc += dv[f] * wv[cc][f];
                o[cc] = (__bf16)acc;
            }
            *(bf16x8_t*)&rowp[512 + side * 256 + c0] = o;
        }
    } else {
        *(bf16x8_t*)&rowp[512 + c0] =
            *(const bf16x8_t*)&hprev[((size_t)b * (2 * n) + 2 * m) * HH + c0];
        *(bf16x8_t*)&rowp[768 + c0] =
            *(const bf16x8_t*)&hprev[((size_t)b * (2 * n) + 2 * m + 1) * HH + c0];
    }
}

__global__ __launch_bounds__(256) void final_kernel(
    const __bf16* __restrict__ hfin, const float* __restrict__ Wp,
    const float* __restrict__ bp, float* __restrict__ out)
{
    const int b = blockIdx.x;
    const int t = threadIdx.x;
    __shared__ float red[256];
    red[t] = (float)hfin[(size_t)b * HH + t] * Wp[t];
    __syncthreads();
    for (int s = 128; s > 0; s >>= 1) {
        if (t < s) red[t] += red[t + s];
        __syncthreads();
    }
    if (t == 0) out[b] = red[0] + bp[0];
}

extern "C" void kernel_launch(void* const* d_in, const int* in_sizes, int n_in,
                              void* d_out, int out_size, void* d_ws, size_t ws_size,
                              hipStream_t stream)
{
    const float* data = (const float*)d_in[0];
    const float* Wu = (const float*)d_in[1];
    const float* bu = (const float*)d_in[2];
    const float* Wr = (const float*)d_in[3];
    const float* br = (const float*)d_in[4];
    const float* Wh = (const float*)d_in[5];
    const float* bh = (const float*)d_in[6];
    const float* Wz = (const float*)d_in[7];
    const float* bz = (const float*)d_in[8];
    const float* Wp = (const float*)d_in[9];
    const float* bp = (const float*)d_in[10];
    float* out = (float*)d_out;

    const size_t CAP = 32768;
    char* w = (char*)d_ws;
    __bf16* hA = (__bf16*)w;   w += (size_t)65536 * HH * 2;
    __bf16* hB = (__bf16*)w;   w += (size_t)32768 * HH * 2;
    __bf16* hhhu = (__bf16*)w; w += CAP * 1024 * 2;
    __bf16* rh = (__bf16*)w;   w += CAP * 768 * 2;
    __bf16* Wrb = (__bf16*)w;  w += (size_t)768 * 768 * 2;
    __bf16* Whb = (__bf16*)w;  w += (size_t)256 * 768 * 2;
    __bf16* Wzb = (__bf16*)w;  w += (size_t)1024 * 1024 * 2;
    float* bzp = (float*)w;    w += 1024 * 4;

    convert_weights<<<2048, 256, 0, stream>>>(Wr, Wh, Wz, bz, Wrb, Whb, Wzb, bzp);

    for (int l = DEPTH - 1; l >= 0; --l) {
        const size_t M = (size_t)BB << l;
        __bf16* dst = ((DEPTH - 1 - l) & 1) ? hB : hA;
        const __bf16* src = ((DEPTH - 1 - l) & 1) ? hA : hB;  // unused at l=8
        for (size_t r0 = 0; r0 < M; r0 += CAP) {
            const int R = (int)((M - r0 < CAP) ? (M - r0) : CAP);
            build_hhu<<<R / 8, 256, 0, stream>>>(data, Wu, bu, src, hhhu, l, (int)r0);
            if (R >= 2048) {
                gemm256w<EPI_SIGMUL><<<dim3(3, R / 256), 1024, 0, stream>>>(
                    hhhu + 256, 1024, Wrb, br, hhhu + 256, 1024, rh, 768, 768);
            } else {
                gemm_mfma<EPI_SIGMUL><<<dim3(6, R / 128), 256, 0, stream>>>(
                    hhhu + 256, 1024, Wrb, br, hhhu + 256, 1024, rh, 768, 768);
            }
            gemm_mfma<EPI_RELU><<<dim3(2, R / 128), 256, 0, stream>>>(
                rh, 768, Whb, bh, nullptr, 0, hhhu, 1024, 768);
            if (R >= 2048) {
                gemm256w<EPI_COMBINE><<<dim3(4, R / 256), 1024, 0, stream>>>(
                    hhhu, 1024, Wzb, bzp, hhhu, 1024,
                    dst + (size_t)r0 * HH, HH, 1024);
            } else {
                gemm_mfma<EPI_COMBINE><<<dim3(8, R / 128), 256, 0, stream>>>(
                    hhhu, 1024, Wzb, bzp, hhhu, 1024,
                    dst + (size_t)r0 * HH, HH, 1024);
            }
        }
    }
    final_kernel<<<BB, 256, 0, stream>>>(hA, Wp, bp, out);
}

// Round 11
// 1196.795 us; speedup vs baseline: 1.3449x; 1.0264x over previous
//
#include <hip/hip_runtime.h>
#include <math.h>

#define BB 256
#define NN 1023
#define FF 8
#define HH 256
#define DEPTH 9

enum { EPI_NONE = 0, EPI_SIGMUL = 1, EPI_RELU = 2, EPI_COMBINE = 3 };

typedef __bf16 bf16x8_t __attribute__((ext_vector_type(8)));
typedef float f32x4_t __attribute__((ext_vector_type(4)));

__device__ __forceinline__ void stage16(const void* g, void* l) {
    __builtin_amdgcn_global_load_lds(
        (const __attribute__((address_space(1))) void*)g,
        (__attribute__((address_space(3))) void*)l,
        16, 0, 0);
}

__device__ __forceinline__ int xcd_remap(int hw, int nwg) {
    const int xcd = hw & 7, k0 = hw >> 3;
    const int qq = nwg >> 3, rr = nwg & 7;
    return (xcd < rr ? xcd * (qq + 1) : rr * (qq + 1) + (xcd - rr) * qq) + k0;
}

// ======== 256x256 tile, BK=64, 16 waves (64x64 C each), counted vmcnt =======
// K-loop identical to round 10. COMBINE epilogue now bounces h through a dead
// LDS panel: scattered 32B writes -> one barrier -> coalesced 128B-row flush.
template <int EPI>
__global__ __launch_bounds__(1024, 4) void gemm256w(
    const __bf16* __restrict__ A, int lda,
    const __bf16* __restrict__ W,       // Nc x K row-major
    const float* __restrict__ bias,
    const __bf16* __restrict__ aux, int ldaux,
    void* __restrict__ Cout, int ldc,
    int K)
{
    __shared__ __bf16 lds[2][2][256 * 64];  // 128 KiB
    const int tid = threadIdx.x;
    const int lane = tid & 63;
    const int w = tid >> 6;            // 0..15
    const int wr = w >> 2, wc = w & 3; // per-wave C = 64x64

    const int nwg = gridDim.x * gridDim.y;
    const int hw = blockIdx.y * gridDim.x + blockIdx.x;
    const int wg = xcd_remap(hw, nwg);
    const int bm0 = (wg / gridDim.x) * 256;
    const int bn0 = (wg % gridDim.x) * 256;

    const int srow = tid >> 3;                       // 0..127
    const int scolz = ((tid & 7) ^ (srow & 7)) * 8;  // inv-swizzled col

    f32x4_t acc[4][4];
#pragma unroll
    for (int i = 0; i < 4; ++i)
#pragma unroll
        for (int j = 0; j < 4; ++j) acc[i][j] = (f32x4_t){0.f, 0.f, 0.f, 0.f};

    const int rA = lane & 15;
    const int klane = (lane >> 4) * 8;
    const int rxor = (lane & 7) * 8;
    const int NT = K >> 6;

#define STAGE_T(t, buf)                                                        \
    do {                                                                       \
        const int kk_ = (t) << 6;                                              \
        stage16(A + (size_t)(bm0 + srow) * lda + kk_ + scolz,                  \
                &lds[buf][0][w * 512]);                                        \
        stage16(A + (size_t)(bm0 + 128 + srow) * lda + kk_ + scolz,            \
                &lds[buf][0][8192 + w * 512]);                                 \
        stage16(W + (size_t)(bn0 + srow) * K + kk_ + scolz,                    \
                &lds[buf][1][w * 512]);                                        \
        stage16(W + (size_t)(bn0 + 128 + srow) * K + kk_ + scolz,              \
                &lds[buf][1][8192 + w * 512]);                                 \
    } while (0)
#define LDA_F(As_, i, ks) \
    (*(const bf16x8_t*)&(As_)[(wr * 64 + (i) * 16 + rA) * 64 + (((ks) * 32 + klane) ^ rxor)])
#define LDB_F(Bs_, j, ks) \
    (*(const bf16x8_t*)&(Bs_)[(wc * 64 + (j) * 16 + rA) * 64 + (((ks) * 32 + klane) ^ rxor)])

    STAGE_T(0, 0);
    STAGE_T(1, 1);
    asm volatile("s_waitcnt vmcnt(4)" ::: "memory");
    __builtin_amdgcn_s_barrier();

    for (int t = 0; t < NT; ++t) {
        const int cur = t & 1;
        const __bf16* As = lds[cur][0];
        const __bf16* Bs = lds[cur][1];
        bf16x8_t af[4], bf[4];

#pragma unroll
        for (int j = 0; j < 4; ++j) bf[j] = LDB_F(Bs, j, 0);
#pragma unroll
        for (int i = 0; i < 4; ++i) af[i] = LDA_F(As, i, 0);
#pragma unroll
        for (int i = 0; i < 4; ++i)
#pragma unroll
            for (int j = 0; j < 4; ++j)
                acc[i][j] = __builtin_amdgcn_mfma_f32_16x16x32_bf16(
                    af[i], bf[j], acc[i][j], 0, 0, 0);
#pragma unroll
        for (int j = 0; j < 4; ++j) bf[j] = LDB_F(Bs, j, 1);
#pragma unroll
        for (int i = 0; i < 4; ++i) af[i] = LDA_F(As, i, 1);
#pragma unroll
        for (int i = 0; i < 2; ++i)
#pragma unroll
            for (int j = 0; j < 4; ++j)
                acc[i][j] = __builtin_amdgcn_mfma_f32_16x16x32_bf16(
                    af[i], bf[j], acc[i][j], 0, 0, 0);

        asm volatile("s_waitcnt lgkmcnt(0)" ::: "memory");
        __builtin_amdgcn_s_barrier();
        if (t + 2 < NT) STAGE_T(t + 2, cur);

        __builtin_amdgcn_s_setprio(1);
#pragma unroll
        for (int i = 2; i < 4; ++i)
#pragma unroll
            for (int j = 0; j < 4; ++j)
                acc[i][j] = __builtin_amdgcn_mfma_f32_16x16x32_bf16(
                    af[i], bf[j], acc[i][j], 0, 0, 0);
        __builtin_amdgcn_s_setprio(0);

        if (t + 1 < NT) {
            if (t + 2 < NT) {
                asm volatile("s_waitcnt vmcnt(4)" ::: "memory");
            } else {
                asm volatile("s_waitcnt vmcnt(0)" ::: "memory");
            }
            __builtin_amdgcn_s_barrier();
        }
    }
#undef STAGE_T
#undef LDA_F
#undef LDB_F

    const int hi = lane >> 4;
    const int r = lane & 15;

    if (EPI == EPI_COMBINE) {
        // h through LDS panel (dead after K-loop): kill 32B-segment writes.
        __bf16* pan = &lds[0][0][0];  // [256][72]
        const int g0 = bn0 >> 2;
        float bz4[4];
#pragma unroll
        for (int g = 0; g < 4; ++g) bz4[g] = bias[bn0 + wc * 64 + g * 16 + r];
        const int G = g0 + wc * 16 + r;
#pragma unroll
        for (int i = 0; i < 4; ++i) {
#pragma unroll
            for (int reg = 0; reg < 4; ++reg) {
                const int lr = wr * 64 + i * 16 + hi * 4 + reg;
                const int gr = bm0 + lr;
                float z0 = acc[i][0][reg] + bz4[0];
                float z1 = acc[i][1][reg] + bz4[1];
                float z2 = acc[i][2][reg] + bz4[2];
                float z3 = acc[i][3][reg] + bz4[3];
                float mx = fmaxf(fmaxf(z0, z1), fmaxf(z2, z3));
                float e0 = __expf(z0 - mx), e1 = __expf(z1 - mx);
                float e2 = __expf(z2 - mx), e3 = __expf(z3 - mx);
                const __bf16* hrow = aux + (size_t)gr * ldaux + G;
                float hv = (e0 * (float)hrow[0] + e1 * (float)hrow[256] +
                            e2 * (float)hrow[512] + e3 * (float)hrow[768]) /
                           (e0 + e1 + e2 + e3);
                pan[lr * 72 + wc * 16 + r] = (__bf16)hv;
            }
        }
        __syncthreads();
#pragma unroll
        for (int it = 0; it < 2; ++it) {
            const int unit = it * 1024 + tid;
            const int row = unit >> 3;
            const int c8 = (unit & 7) * 8;
            bf16x8_t vv = *(const bf16x8_t*)&pan[row * 72 + c8];
            *(bf16x8_t*)((__bf16*)Cout + (size_t)(bm0 + row) * ldc + g0 + c8) = vv;
        }
    } else {
#pragma unroll
        for (int j = 0; j < 4; ++j) {
            const int gc = bn0 + wc * 64 + j * 16 + r;
            const float bv = bias[gc];
#pragma unroll
            for (int i = 0; i < 4; ++i) {
#pragma unroll
                for (int reg = 0; reg < 4; ++reg) {
                    const int gr = bm0 + wr * 64 + i * 16 + hi * 4 + reg;
                    float v = acc[i][j][reg] + bv;
                    if (EPI == EPI_SIGMUL) {
                        float s = 1.0f / (1.0f + __expf(-v));
                        v = s * (float)aux[(size_t)gr * ldaux + gc];
                        ((__bf16*)Cout)[(size_t)gr * ldc + gc] = (__bf16)v;
                    } else if (EPI == EPI_RELU) {
                        v = fmaxf(v, 0.0f);
                        ((__bf16*)Cout)[(size_t)gr * ldc + gc] = (__bf16)v;
                    } else {
                        ((float*)Cout)[(size_t)gr * ldc + gc] = v;
                    }
                }
            }
        }
    }
}

// ---------------- 128x128-tile kernel (proven; Wh + small/mid levels) -------
template <int EPI>
__global__ __launch_bounds__(256) void gemm_mfma(
    const __bf16* __restrict__ A, int lda,
    const __bf16* __restrict__ W,
    const float* __restrict__ bias,
    const __bf16* __restrict__ aux, int ldaux,
    void* __restrict__ Cout, int ldc,
    int K)
{
    __shared__ __bf16 As[128 * 32];
    __shared__ __bf16 Bs[128 * 32];
    const int tid = threadIdx.x;
    const int lane = tid & 63;
    const int w = tid >> 6;
    const int wr = w >> 1, wc = w & 1;

    const int nwg = gridDim.x * gridDim.y;
    const int hw = blockIdx.y * gridDim.x + blockIdx.x;
    const int wg = xcd_remap(hw, nwg);
    const int bm0 = (wg / gridDim.x) * 128;
    const int bn0 = (wg % gridDim.x) * 128;

    const int srow = lane >> 2;
    const int scol = (lane & 3) * 8;

    f32x4_t acc[4][4];
#pragma unroll
    for (int i = 0; i < 4; ++i)
#pragma unroll
        for (int j = 0; j < 4; ++j) acc[i][j] = (f32x4_t){0.f, 0.f, 0.f, 0.f};

    const int rA = lane & 15;
    const int kslot = (lane >> 4) * 8;

    for (int kk = 0; kk < K; kk += 32) {
        stage16(A + (size_t)(bm0 + w * 16 + srow) * lda + kk + scol,
                &As[(w * 16) * 32]);
        stage16(A + (size_t)(bm0 + 64 + w * 16 + srow) * lda + kk + scol,
                &As[(64 + w * 16) * 32]);
        stage16(W + (size_t)(bn0 + w * 16 + srow) * K + kk + scol,
                &Bs[(w * 16) * 32]);
        stage16(W + (size_t)(bn0 + 64 + w * 16 + srow) * K + kk + scol,
                &Bs[(64 + w * 16) * 32]);
        __syncthreads();

        bf16x8_t af[4], bfr[4];
#pragma unroll
        for (int i = 0; i < 4; ++i)
            af[i] = *(const bf16x8_t*)&As[(wr * 64 + i * 16 + rA) * 32 + kslot];
#pragma unroll
        for (int j = 0; j < 4; ++j)
            bfr[j] = *(const bf16x8_t*)&Bs[(wc * 64 + j * 16 + rA) * 32 + kslot];
#pragma unroll
        for (int i = 0; i < 4; ++i)
#pragma unroll
            for (int j = 0; j < 4; ++j)
                acc[i][j] = __builtin_amdgcn_mfma_f32_16x16x32_bf16(
                    af[i], bfr[j], acc[i][j], 0, 0, 0);
        __syncthreads();
    }

    if (EPI == EPI_COMBINE) {
        const int r = lane & 15;
        const int G = ((bn0 + wc * 64) >> 2) + r;
        float bz4[4];
#pragma unroll
        for (int g = 0; g < 4; ++g) bz4[g] = bias[bn0 + wc * 64 + g * 16 + r];
#pragma unroll
        for (int i = 0; i < 4; ++i) {
#pragma unroll
            for (int reg = 0; reg < 4; ++reg) {
                const int gr = bm0 + wr * 64 + i * 16 + (lane >> 4) * 4 + reg;
                float z0 = acc[i][0][reg] + bz4[0];
                float z1 = acc[i][1][reg] + bz4[1];
                float z2 = acc[i][2][reg] + bz4[2];
                float z3 = acc[i][3][reg] + bz4[3];
                float mx = fmaxf(fmaxf(z0, z1), fmaxf(z2, z3));
                float e0 = __expf(z0 - mx), e1 = __expf(z1 - mx);
                float e2 = __expf(z2 - mx), e3 = __expf(z3 - mx);
                const __bf16* hrow = aux + (size_t)gr * ldaux + G;
                float hv = (e0 * (float)hrow[0] + e1 * (float)hrow[256] +
                            e2 * (float)hrow[512] + e3 * (float)hrow[768]) /
                           (e0 + e1 + e2 + e3);
                ((__bf16*)Cout)[(size_t)gr * ldc + G] = (__bf16)hv;
            }
        }
    } else {
#pragma unroll
        for (int j = 0; j < 4; ++j) {
            const int gc = bn0 + wc * 64 + j * 16 + (lane & 15);
            const float bv = bias[gc];
#pragma unroll
            for (int i = 0; i < 4; ++i) {
#pragma unroll
                for (int reg = 0; reg < 4; ++reg) {
                    const int gr = bm0 + wr * 64 + i * 16 + (lane >> 4) * 4 + reg;
                    float v = acc[i][j][reg] + bv;
                    if (EPI == EPI_SIGMUL) {
                        float s = 1.0f / (1.0f + __expf(-v));
                        v = s * (float)aux[(size_t)gr * ldaux + gc];
                        ((__bf16*)Cout)[(size_t)gr * ldc + gc] = (__bf16)v;
                    } else if (EPI == EPI_RELU) {
                        v = fmaxf(v, 0.0f);
                        ((__bf16*)Cout)[(size_t)gr * ldc + gc] = (__bf16)v;
                    } else {
                        ((float*)Cout)[(size_t)gr * ldc + gc] = v;
                    }
                }
            }
        }
    }
}

// Wr/Wh -> bf16; Wz -> bf16 with softmax-group row permutation.
__global__ __launch_bounds__(256) void convert_weights(
    const float* __restrict__ Wr, const float* __restrict__ Wh,
    const float* __restrict__ Wz, const float* __restrict__ bz,
    __bf16* __restrict__ Wrb, __bf16* __restrict__ Whb,
    __bf16* __restrict__ Wzb, float* __restrict__ bzp)
{
    const int NR = 768 * 768, NH2 = 256 * 768, NZ = 1024 * 1024;
    const int idx0 = blockIdx.x * 256 + threadIdx.x;
    for (int i = idx0; i < NR + NH2 + NZ; i += gridDim.x * 256) {
        if (i < NR) Wrb[i] = (__bf16)Wr[i];
        else if (i < NR + NH2) Whb[i - NR] = (__bf16)Wh[i - NR];
        else {
            const int z = i - NR - NH2;
            const int p = z >> 10, k = z & 1023;
            const int o = ((p >> 4) & 3) * 256 + (p >> 6) * 16 + (p & 15);
            Wzb[z] = (__bf16)Wz[(size_t)o * 1024 + k];
        }
    }
    if (idx0 < 1024) {
        const int p = idx0;
        const int o = ((p >> 4) & 3) * 256 + (p >> 6) * 16 + (p & 15);
        bzp[p] = bz[o];
    }
}

// hhhu cols 256..1024 = [parent_u, h_l, h_r]; 8 rows/block, 8 cols/thread.
__global__ __launch_bounds__(256) void build_hhu(
    const float* __restrict__ data, const float* __restrict__ Wu,
    const float* __restrict__ bu, const __bf16* __restrict__ hprev,
    __bf16* __restrict__ hhhu, int l, int r0)
{
    const int n = 1 << l;
    const int blk = xcd_remap(blockIdx.x, gridDim.x);
    const int row = blk * 8 + (threadIdx.x >> 5);
    const int c0 = (threadIdx.x & 31) * 8;
    const int i = r0 + row;
    const int b = i >> l;
    const int m = i & (n - 1);

    float wv[8][8];
#pragma unroll
    for (int cc = 0; cc < 8; ++cc) {
        float4 w0 = *(const float4*)&Wu[(c0 + cc) * 8];
        float4 w1 = *(const float4*)&Wu[(c0 + cc) * 8 + 4];
        wv[cc][0] = w0.x; wv[cc][1] = w0.y; wv[cc][2] = w0.z; wv[cc][3] = w0.w;
        wv[cc][4] = w1.x; wv[cc][5] = w1.y; wv[cc][6] = w1.z; wv[cc][7] = w1.w;
    }
    float buv[8];
#pragma unroll
    for (int cc = 0; cc < 8; ++cc) buv[cc] = bu[c0 + cc];

    __bf16* rowp = hhhu + (size_t)row * 1024;

    {
        const float* dp = data + ((size_t)b * NN + (n - 1) + m) * FF;
        float4 d0 = *(const float4*)dp, d1 = *(const float4*)(dp + 4);
        float dv[8] = {d0.x, d0.y, d0.z, d0.w, d1.x, d1.y, d1.z, d1.w};
        bf16x8_t o;
#pragma unroll
        for (int cc = 0; cc < 8; ++cc) {
            float acc = buv[cc];
#pragma unroll
            for (int f = 0; f < 8; ++f) acc += dv[f] * wv[cc][f];
            o[cc] = (__bf16)acc;
        }
        *(bf16x8_t*)&rowp[256 + c0] = o;
    }

    if (l == 8) {
        const float* dl = data + ((size_t)b * NN + 511 + 2 * m) * FF;
#pragma unroll
        for (int side = 0; side < 2; ++side) {
            const float* dp = dl + side * FF;
            float4 d0 = *(const float4*)dp, d1 = *(const float4*)(dp + 4);
            float dv[8] = {d0.x, d0.y, d0.z, d0.w, d1.x, d1.y, d1.z, d1.w};
            bf16x8_t o;
#pragma unroll
            for (int cc = 0; cc < 8; ++cc) {
                float acc = buv[cc];
#pragma unroll
                for (int f = 0; f < 8; ++f) acc += dv[f] * wv[cc][f];
                o[cc] = (__bf16)acc;
            }
            *(bf16x8_t*)&rowp[512 + side * 256 + c0] = o;
        }
    } else {
        *(bf16x8_t*)&rowp[512 + c0] =
            *(const bf16x8_t*)&hprev[((size_t)b * (2 * n) + 2 * m) * HH + c0];
        *(bf16x8_t*)&rowp[768 + c0] =
            *(const bf16x8_t*)&hprev[((size_t)b * (2 * n) + 2 * m + 1) * HH + c0];
    }
}

__global__ __launch_bounds__(256) void final_kernel(
    const __bf16* __restrict__ hfin, const float* __restrict__ Wp,
    const float* __restrict__ bp, float* __restrict__ out)
{
    const int b = blockIdx.x;
    const int t = threadIdx.x;
    __shared__ float red[256];
    red[t] = (float)hfin[(size_t)b * HH + t] * Wp[t];
    __syncthreads();
    for (int s = 128; s > 0; s >>= 1) {
        if (t < s) red[t] += red[t + s];
        __syncthreads();
    }
    if (t == 0) out[b] = red[0] + bp[0];
}

extern "C" void kernel_launch(void* const* d_in, const int* in_sizes, int n_in,
                              void* d_out, int out_size, void* d_ws, size_t ws_size,
                              hipStream_t stream)
{
    const float* data = (const float*)d_in[0];
    const float* Wu = (const float*)d_in[1];
    const float* bu = (const float*)d_in[2];
    const float* Wr = (const float*)d_in[3];
    const float* br = (const float*)d_in[4];
    const float* Wh = (const float*)d_in[5];
    const float* bh = (const float*)d_in[6];
    const float* Wz = (const float*)d_in[7];
    const float* bz = (const float*)d_in[8];
    const float* Wp = (const float*)d_in[9];
    const float* bp = (const float*)d_in[10];
    float* out = (float*)d_out;

    const size_t CAP = 32768;
    char* w = (char*)d_ws;
    __bf16* hA = (__bf16*)w;   w += (size_t)65536 * HH * 2;
    __bf16* hB = (__bf16*)w;   w += (size_t)32768 * HH * 2;
    __bf16* hhhu = (__bf16*)w; w += CAP * 1024 * 2;
    __bf16* rh = (__bf16*)w;   w += CAP * 768 * 2;
    __bf16* Wrb = (__bf16*)w;  w += (size_t)768 * 768 * 2;
    __bf16* Whb = (__bf16*)w;  w += (size_t)256 * 768 * 2;
    __bf16* Wzb = (__bf16*)w;  w += (size_t)1024 * 1024 * 2;
    float* bzp = (float*)w;    w += 1024 * 4;

    convert_weights<<<2048, 256, 0, stream>>>(Wr, Wh, Wz, bz, Wrb, Whb, Wzb, bzp);

    for (int l = DEPTH - 1; l >= 0; --l) {
        const size_t M = (size_t)BB << l;
        __bf16* dst = ((DEPTH - 1 - l) & 1) ? hB : hA;
        const __bf16* src = ((DEPTH - 1 - l) & 1) ? hA : hB;  // unused at l=8
        for (size_t r0 = 0; r0 < M; r0 += CAP) {
            const int R = (int)((M - r0 < CAP) ? (M - r0) : CAP);
            build_hhu<<<R / 8, 256, 0, stream>>>(data, Wu, bu, src, hhhu, l, (int)r0);
            if (R >= 32768) {
                gemm256w<EPI_SIGMUL><<<dim3(3, R / 256), 1024, 0, stream>>>(
                    hhhu + 256, 1024, Wrb, br, hhhu + 256, 1024, rh, 768, 768);
            } else {
                gemm_mfma<EPI_SIGMUL><<<dim3(6, R / 128), 256, 0, stream>>>(
                    hhhu + 256, 1024, Wrb, br, hhhu + 256, 1024, rh, 768, 768);
            }
            gemm_mfma<EPI_RELU><<<dim3(2, R / 128), 256, 0, stream>>>(
                rh, 768, Whb, bh, nullptr, 0, hhhu, 1024, 768);
            if (R >= 16384) {
                gemm256w<EPI_COMBINE><<<dim3(4, R / 256), 1024, 0, stream>>>(
                    hhhu, 1024, Wzb, bzp, hhhu, 1024,
                    dst + (size_t)r0 * HH, HH, 1024);
            } else {
                gemm_mfma<EPI_COMBINE><<<dim3(8, R / 128), 256, 0, stream>>>(
                    hhhu, 1024, Wzb, bzp, hhhu, 1024,
                    dst + (size_t)r0 * HH, HH, 1024);
            }
        }
    }
    final_kernel<<<BB, 256, 0, stream>>>(hA, Wp, bp, out);
}

// Round 12
// 1185.662 us; speedup vs baseline: 1.3576x; 1.0094x over previous
//
#include <hip/hip_runtime.h>
#include <math.h>

#define BB 256
#define NN 1023
#define FF 8
#define HH 256
#define DEPTH 9

enum { EPI_NONE = 0, EPI_SIGMUL = 1, EPI_RELU = 2, EPI_COMBINE = 3 };

typedef __bf16 bf16x8_t __attribute__((ext_vector_type(8)));
typedef float f32x4_t __attribute__((ext_vector_type(4)));

__device__ __forceinline__ void stage16(const void* g, void* l) {
    __builtin_amdgcn_global_load_lds(
        (const __attribute__((address_space(1))) void*)g,
        (__attribute__((address_space(3))) void*)l,
        16, 0, 0);
}

__device__ __forceinline__ int xcd_remap(int hw, int nwg) {
    const int xcd = hw & 7, k0 = hw >> 3;
    const int qq = nwg >> 3, rr = nwg & 7;
    return (xcd < rr ? xcd * (qq + 1) : rr * (qq + 1) + (xcd - rr) * qq) + k0;
}

// ======== 256x256 tile, BK=64, 16 waves (64x64 C each), counted vmcnt =======
// K-loop identical to round 10/11. Epilogues route C through the dead 128 KiB
// LDS so all global writes are bf16x8 coalesced (COMBINE kept from r11;
// SIGMUL added this round — write-only bounce, no aux restaging).
template <int EPI>
__global__ __launch_bounds__(1024, 4) void gemm256w(
    const __bf16* __restrict__ A, int lda,
    const __bf16* __restrict__ W,       // Nc x K row-major
    const float* __restrict__ bias,
    const __bf16* __restrict__ aux, int ldaux,
    void* __restrict__ Cout, int ldc,
    int K)
{
    __shared__ __bf16 lds[2][2][256 * 64];  // 128 KiB
    const int tid = threadIdx.x;
    const int lane = tid & 63;
    const int w = tid >> 6;            // 0..15
    const int wr = w >> 2, wc = w & 3; // per-wave C = 64x64

    const int nwg = gridDim.x * gridDim.y;
    const int hw = blockIdx.y * gridDim.x + blockIdx.x;
    const int wg = xcd_remap(hw, nwg);
    const int bm0 = (wg / gridDim.x) * 256;
    const int bn0 = (wg % gridDim.x) * 256;

    const int srow = tid >> 3;                       // 0..127
    const int scolz = ((tid & 7) ^ (srow & 7)) * 8;  // inv-swizzled col

    f32x4_t acc[4][4];
#pragma unroll
    for (int i = 0; i < 4; ++i)
#pragma unroll
        for (int j = 0; j < 4; ++j) acc[i][j] = (f32x4_t){0.f, 0.f, 0.f, 0.f};

    const int rA = lane & 15;
    const int klane = (lane >> 4) * 8;
    const int rxor = (lane & 7) * 8;
    const int NT = K >> 6;

#define STAGE_T(t, buf)                                                        \
    do {                                                                       \
        const int kk_ = (t) << 6;                                              \
        stage16(A + (size_t)(bm0 + srow) * lda + kk_ + scolz,                  \
                &lds[buf][0][w * 512]);                                        \
        stage16(A + (size_t)(bm0 + 128 + srow) * lda + kk_ + scolz,            \
                &lds[buf][0][8192 + w * 512]);                                 \
        stage16(W + (size_t)(bn0 + srow) * K + kk_ + scolz,                    \
                &lds[buf][1][w * 512]);                                        \
        stage16(W + (size_t)(bn0 + 128 + srow) * K + kk_ + scolz,              \
                &lds[buf][1][8192 + w * 512]);                                 \
    } while (0)
#define LDA_F(As_, i, ks) \
    (*(const bf16x8_t*)&(As_)[(wr * 64 + (i) * 16 + rA) * 64 + (((ks) * 32 + klane) ^ rxor)])
#define LDB_F(Bs_, j, ks) \
    (*(const bf16x8_t*)&(Bs_)[(wc * 64 + (j) * 16 + rA) * 64 + (((ks) * 32 + klane) ^ rxor)])

    STAGE_T(0, 0);
    STAGE_T(1, 1);
    asm volatile("s_waitcnt vmcnt(4)" ::: "memory");
    __builtin_amdgcn_s_barrier();

    for (int t = 0; t < NT; ++t) {
        const int cur = t & 1;
        const __bf16* As = lds[cur][0];
        const __bf16* Bs = lds[cur][1];
        bf16x8_t af[4], bf[4];

#pragma unroll
        for (int j = 0; j < 4; ++j) bf[j] = LDB_F(Bs, j, 0);
#pragma unroll
        for (int i = 0; i < 4; ++i) af[i] = LDA_F(As, i, 0);
#pragma unroll
        for (int i = 0; i < 4; ++i)
#pragma unroll
            for (int j = 0; j < 4; ++j)
                acc[i][j] = __builtin_amdgcn_mfma_f32_16x16x32_bf16(
                    af[i], bf[j], acc[i][j], 0, 0, 0);
#pragma unroll
        for (int j = 0; j < 4; ++j) bf[j] = LDB_F(Bs, j, 1);
#pragma unroll
        for (int i = 0; i < 4; ++i) af[i] = LDA_F(As, i, 1);
#pragma unroll
        for (int i = 0; i < 2; ++i)
#pragma unroll
            for (int j = 0; j < 4; ++j)
                acc[i][j] = __builtin_amdgcn_mfma_f32_16x16x32_bf16(
                    af[i], bf[j], acc[i][j], 0, 0, 0);

        asm volatile("s_waitcnt lgkmcnt(0)" ::: "memory");
        __builtin_amdgcn_s_barrier();
        if (t + 2 < NT) STAGE_T(t + 2, cur);

        __builtin_amdgcn_s_setprio(1);
#pragma unroll
        for (int i = 2; i < 4; ++i)
#pragma unroll
            for (int j = 0; j < 4; ++j)
                acc[i][j] = __builtin_amdgcn_mfma_f32_16x16x32_bf16(
                    af[i], bf[j], acc[i][j], 0, 0, 0);
        __builtin_amdgcn_s_setprio(0);

        if (t + 1 < NT) {
            if (t + 2 < NT) {
                asm volatile("s_waitcnt vmcnt(4)" ::: "memory");
            } else {
                asm volatile("s_waitcnt vmcnt(0)" ::: "memory");
            }
            __builtin_amdgcn_s_barrier();
        }
    }
#undef STAGE_T
#undef LDA_F
#undef LDB_F

    const int hi = lane >> 4;
    const int r = lane & 15;

    if (EPI == EPI_COMBINE) {
        // h through LDS panel (dead after K-loop): coalesced flush.
        __bf16* pan = &lds[0][0][0];  // [256][72]
        const int g0 = bn0 >> 2;
        float bz4[4];
#pragma unroll
        for (int g = 0; g < 4; ++g) bz4[g] = bias[bn0 + wc * 64 + g * 16 + r];
        const int G = g0 + wc * 16 + r;
#pragma unroll
        for (int i = 0; i < 4; ++i) {
#pragma unroll
            for (int reg = 0; reg < 4; ++reg) {
                const int lr = wr * 64 + i * 16 + hi * 4 + reg;
                const int gr = bm0 + lr;
                float z0 = acc[i][0][reg] + bz4[0];
                float z1 = acc[i][1][reg] + bz4[1];
                float z2 = acc[i][2][reg] + bz4[2];
                float z3 = acc[i][3][reg] + bz4[3];
                float mx = fmaxf(fmaxf(z0, z1), fmaxf(z2, z3));
                float e0 = __expf(z0 - mx), e1 = __expf(z1 - mx);
                float e2 = __expf(z2 - mx), e3 = __expf(z3 - mx);
                const __bf16* hrow = aux + (size_t)gr * ldaux + G;
                float hv = (e0 * (float)hrow[0] + e1 * (float)hrow[256] +
                            e2 * (float)hrow[512] + e3 * (float)hrow[768]) /
                           (e0 + e1 + e2 + e3);
                pan[lr * 72 + wc * 16 + r] = (__bf16)hv;
            }
        }
        __syncthreads();
#pragma unroll
        for (int it = 0; it < 2; ++it) {
            const int unit = it * 1024 + tid;
            const int row = unit >> 3;
            const int c8 = (unit & 7) * 8;
            bf16x8_t vv = *(const bf16x8_t*)&pan[row * 72 + c8];
            *(bf16x8_t*)((__bf16*)Cout + (size_t)(bm0 + row) * ldc + g0 + c8) = vv;
        }
    } else if (EPI == EPI_SIGMUL) {
        // rh through LDS panel [256][256] (exactly 128 KiB): coalesced flush.
        __bf16* pan = &lds[0][0][0];
        float bv[4];
#pragma unroll
        for (int j = 0; j < 4; ++j) bv[j] = bias[bn0 + wc * 64 + j * 16 + r];
#pragma unroll
        for (int j = 0; j < 4; ++j) {
            const int lc = wc * 64 + j * 16 + r;
            const int gc = bn0 + lc;
#pragma unroll
            for (int i = 0; i < 4; ++i) {
#pragma unroll
                for (int reg = 0; reg < 4; ++reg) {
                    const int lr = wr * 64 + i * 16 + hi * 4 + reg;
                    const int gr = bm0 + lr;
                    float v = acc[i][j][reg] + bv[j];
                    float s = 1.0f / (1.0f + __expf(-v));
                    v = s * (float)aux[(size_t)gr * ldaux + gc];
                    pan[lr * 256 + lc] = (__bf16)v;
                }
            }
        }
        __syncthreads();
#pragma unroll
        for (int it = 0; it < 8; ++it) {
            const int unit = it * 1024 + tid;
            const int row = unit >> 5;
            const int c8 = (unit & 31) * 8;
            bf16x8_t vv = *(const bf16x8_t*)&pan[row * 256 + c8];
            *(bf16x8_t*)((__bf16*)Cout + (size_t)(bm0 + row) * ldc + bn0 + c8) = vv;
        }
    } else {
#pragma unroll
        for (int j = 0; j < 4; ++j) {
            const int gc = bn0 + wc * 64 + j * 16 + r;
            const float bv = bias[gc];
#pragma unroll
            for (int i = 0; i < 4; ++i) {
#pragma unroll
                for (int reg = 0; reg < 4; ++reg) {
                    const int gr = bm0 + wr * 64 + i * 16 + hi * 4 + reg;
                    float v = acc[i][j][reg] + bv;
                    if (EPI == EPI_RELU) v = fmaxf(v, 0.0f);
                    if (EPI == EPI_RELU)
                        ((__bf16*)Cout)[(size_t)gr * ldc + gc] = (__bf16)v;
                    else
                        ((float*)Cout)[(size_t)gr * ldc + gc] = v;
                }
            }
        }
    }
}

// ---------------- 128x128-tile kernel (proven; Wh + small/mid levels) -------
template <int EPI>
__global__ __launch_bounds__(256) void gemm_mfma(
    const __bf16* __restrict__ A, int lda,
    const __bf16* __restrict__ W,
    const float* __restrict__ bias,
    const __bf16* __restrict__ aux, int ldaux,
    void* __restrict__ Cout, int ldc,
    int K)
{
    __shared__ __bf16 As[128 * 32];
    __shared__ __bf16 Bs[128 * 32];
    const int tid = threadIdx.x;
    const int lane = tid & 63;
    const int w = tid >> 6;
    const int wr = w >> 1, wc = w & 1;

    const int nwg = gridDim.x * gridDim.y;
    const int hw = blockIdx.y * gridDim.x + blockIdx.x;
    const int wg = xcd_remap(hw, nwg);
    const int bm0 = (wg / gridDim.x) * 128;
    const int bn0 = (wg % gridDim.x) * 128;

    const int srow = lane >> 2;
    const int scol = (lane & 3) * 8;

    f32x4_t acc[4][4];
#pragma unroll
    for (int i = 0; i < 4; ++i)
#pragma unroll
        for (int j = 0; j < 4; ++j) acc[i][j] = (f32x4_t){0.f, 0.f, 0.f, 0.f};

    const int rA = lane & 15;
    const int kslot = (lane >> 4) * 8;

    for (int kk = 0; kk < K; kk += 32) {
        stage16(A + (size_t)(bm0 + w * 16 + srow) * lda + kk + scol,
                &As[(w * 16) * 32]);
        stage16(A + (size_t)(bm0 + 64 + w * 16 + srow) * lda + kk + scol,
                &As[(64 + w * 16) * 32]);
        stage16(W + (size_t)(bn0 + w * 16 + srow) * K + kk + scol,
                &Bs[(w * 16) * 32]);
        stage16(W + (size_t)(bn0 + 64 + w * 16 + srow) * K + kk + scol,
                &Bs[(64 + w * 16) * 32]);
        __syncthreads();

        bf16x8_t af[4], bfr[4];
#pragma unroll
        for (int i = 0; i < 4; ++i)
            af[i] = *(const bf16x8_t*)&As[(wr * 64 + i * 16 + rA) * 32 + kslot];
#pragma unroll
        for (int j = 0; j < 4; ++j)
            bfr[j] = *(const bf16x8_t*)&Bs[(wc * 64 + j * 16 + rA) * 32 + kslot];
#pragma unroll
        for (int i = 0; i < 4; ++i)
#pragma unroll
            for (int j = 0; j < 4; ++j)
                acc[i][j] = __builtin_amdgcn_mfma_f32_16x16x32_bf16(
                    af[i], bfr[j], acc[i][j], 0, 0, 0);
        __syncthreads();
    }

    if (EPI == EPI_COMBINE) {
        const int r = lane & 15;
        const int G = ((bn0 + wc * 64) >> 2) + r;
        float bz4[4];
#pragma unroll
        for (int g = 0; g < 4; ++g) bz4[g] = bias[bn0 + wc * 64 + g * 16 + r];
#pragma unroll
        for (int i = 0; i < 4; ++i) {
#pragma unroll
            for (int reg = 0; reg < 4; ++reg) {
                const int gr = bm0 + wr * 64 + i * 16 + (lane >> 4) * 4 + reg;
                float z0 = acc[i][0][reg] + bz4[0];
                float z1 = acc[i][1][reg] + bz4[1];
                float z2 = acc[i][2][reg] + bz4[2];
                float z3 = acc[i][3][reg] + bz4[3];
                float mx = fmaxf(fmaxf(z0, z1), fmaxf(z2, z3));
                float e0 = __expf(z0 - mx), e1 = __expf(z1 - mx);
                float e2 = __expf(z2 - mx), e3 = __expf(z3 - mx);
                const __bf16* hrow = aux + (size_t)gr * ldaux + G;
                float hv = (e0 * (float)hrow[0] + e1 * (float)hrow[256] +
                            e2 * (float)hrow[512] + e3 * (float)hrow[768]) /
                           (e0 + e1 + e2 + e3);
                ((__bf16*)Cout)[(size_t)gr * ldc + G] = (__bf16)hv;
            }
        }
    } else {
#pragma unroll
        for (int j = 0; j < 4; ++j) {
            const int gc = bn0 + wc * 64 + j * 16 + (lane & 15);
            const float bv = bias[gc];
#pragma unroll
            for (int i = 0; i < 4; ++i) {
#pragma unroll
                for (int reg = 0; reg < 4; ++reg) {
                    const int gr = bm0 + wr * 64 + i * 16 + (lane >> 4) * 4 + reg;
                    float v = acc[i][j][reg] + bv;
                    if (EPI == EPI_SIGMUL) {
                        float s = 1.0f / (1.0f + __expf(-v));
                        v = s * (float)aux[(size_t)gr * ldaux + gc];
                        ((__bf16*)Cout)[(size_t)gr * ldc + gc] = (__bf16)v;
                    } else if (EPI == EPI_RELU) {
                        v = fmaxf(v, 0.0f);
                        ((__bf16*)Cout)[(size_t)gr * ldc + gc] = (__bf16)v;
                    } else {
                        ((float*)Cout)[(size_t)gr * ldc + gc] = v;
                    }
                }
            }
        }
    }
}

// Wr/Wh -> bf16; Wz -> bf16 with softmax-group row permutation.
__global__ __launch_bounds__(256) void convert_weights(
    const float* __restrict__ Wr, const float* __restrict__ Wh,
    const float* __restrict__ Wz, const float* __restrict__ bz,
    __bf16* __restrict__ Wrb, __bf16* __restrict__ Whb,
    __bf16* __restrict__ Wzb, float* __restrict__ bzp)
{
    const int NR = 768 * 768, NH2 = 256 * 768, NZ = 1024 * 1024;
    const int idx0 = blockIdx.x * 256 + threadIdx.x;
    for (int i = idx0; i < NR + NH2 + NZ; i += gridDim.x * 256) {
        if (i < NR) Wrb[i] = (__bf16)Wr[i];
        else if (i < NR + NH2) Whb[i - NR] = (__bf16)Wh[i - NR];
        else {
            const int z = i - NR - NH2;
            const int p = z >> 10, k = z & 1023;
            const int o = ((p >> 4) & 3) * 256 + (p >> 6) * 16 + (p & 15);
            Wzb[z] = (__bf16)Wz[(size_t)o * 1024 + k];
        }
    }
    if (idx0 < 1024) {
        const int p = idx0;
        const int o = ((p >> 4) & 3) * 256 + (p >> 6) * 16 + (p & 15);
        bzp[p] = bz[o];
    }
}

// hhhu cols 256..1024 = [parent_u, h_l, h_r]; 8 rows/block, 8 cols/thread.
__global__ __launch_bounds__(256) void build_hhu(
    const float* __restrict__ data, const float* __restrict__ Wu,
    const float* __restrict__ bu, const __bf16* __restrict__ hprev,
    __bf16* __restrict__ hhhu, int l, int r0)
{
    const int n = 1 << l;
    const int blk = xcd_remap(blockIdx.x, gridDim.x);
    const int row = blk * 8 + (threadIdx.x >> 5);
    const int c0 = (threadIdx.x & 31) * 8;
    const int i = r0 + row;
    const int b = i >> l;
    const int m = i & (n - 1);

    float wv[8][8];
#pragma unroll
    for (int cc = 0; cc < 8; ++cc) {
        float4 w0 = *(const float4*)&Wu[(c0 + cc) * 8];
        float4 w1 = *(const float4*)&Wu[(c0 + cc) * 8 + 4];
        wv[cc][0] = w0.x; wv[cc][1] = w0.y; wv[cc][2] = w0.z; wv[cc][3] = w0.w;
        wv[cc][4] = w1.x; wv[cc][5] = w1.y; wv[cc][6] = w1.z; wv[cc][7] = w1.w;
    }
    float buv[8];
#pragma unroll
    for (int cc = 0; cc < 8; ++cc) buv[cc] = bu[c0 + cc];

    __bf16* rowp = hhhu + (size_t)row * 1024;

    {
        const float* dp = data + ((size_t)b * NN + (n - 1) + m) * FF;
        float4 d0 = *(const float4*)dp, d1 = *(const float4*)(dp + 4);
        float dv[8] = {d0.x, d0.y, d0.z, d0.w, d1.x, d1.y, d1.z, d1.w};
        bf16x8_t o;
#pragma unroll
        for (int cc = 0; cc < 8; ++cc) {
            float acc = buv[cc];
#pragma unroll
            for (int f = 0; f < 8; ++f) acc += dv[f] * wv[cc][f];
            o[cc] = (__bf16)acc;
        }
        *(bf16x8_t*)&rowp[256 + c0] = o;
    }

    if (l == 8) {
        const float* dl = data + ((size_t)b * NN + 511 + 2 * m) * FF;
#pragma unroll
        for (int side = 0; side < 2; ++side) {
            const float* dp = dl + side * FF;
            float4 d0 = *(const float4*)dp, d1 = *(const float4*)(dp + 4);
            float dv[8] = {d0.x, d0.y, d0.z, d0.w, d1.x, d1.y, d1.z, d1.w};
            bf16x8_t o;
#pragma unroll
            for (int cc = 0; cc < 8; ++cc) {
                float acc = buv[cc];
#pragma unroll
                for (int f = 0; f < 8; ++f) acc += dv[f] * wv[cc][f];
                o[cc] = (__bf16)acc;
            }
            *(bf16x8_t*)&rowp[512 + side * 256 + c0] = o;
        }
    } else {
        *(bf16x8_t*)&rowp[512 + c0] =
            *(const bf16x8_t*)&hprev[((size_t)b * (2 * n) + 2 * m) * HH + c0];
        *(bf16x8_t*)&rowp[768 + c0] =
            *(const bf16x8_t*)&hprev[((size_t)b * (2 * n) + 2 * m + 1) * HH + c0];
    }
}

__global__ __launch_bounds__(256) void final_kernel(
    const __bf16* __restrict__ hfin, const float* __restrict__ Wp,
    const float* __restrict__ bp, float* __restrict__ out)
{
    const int b = blockIdx.x;
    const int t = threadIdx.x;
    __shared__ float red[256];
    red[t] = (float)hfin[(size_t)b * HH + t] * Wp[t];
    __syncthreads();
    for (int s = 128; s > 0; s >>= 1) {
        if (t < s) red[t] += red[t + s];
        __syncthreads();
    }
    if (t == 0) out[b] = red[0] + bp[0];
}

extern "C" void kernel_launch(void* const* d_in, const int* in_sizes, int n_in,
                              void* d_out, int out_size, void* d_ws, size_t ws_size,
                              hipStream_t stream)
{
    const float* data = (const float*)d_in[0];
    const float* Wu = (const float*)d_in[1];
    const float* bu = (const float*)d_in[2];
    const float* Wr = (const float*)d_in[3];
    const float* br = (const float*)d_in[4];
    const float* Wh = (const float*)d_in[5];
    const float* bh = (const float*)d_in[6];
    const float* Wz = (const float*)d_in[7];
    const float* bz = (const float*)d_in[8];
    const float* Wp = (const float*)d_in[9];
    const float* bp = (const float*)d_in[10];
    float* out = (float*)d_out;

    // CAP=16384: per-XCD activation slices (hhu 3.1 MB, rh 3.1 MB) mostly fit
    // the 4 MiB per-XCD L2; xcd_remap gives ALL kernels the same contiguous
    // row-range -> XCD mapping, so producer writes are consumer L2 hits.
    const size_t CAP = 16384;
    char* w = (char*)d_ws;
    __bf16* hA = (__bf16*)w;   w += (size_t)65536 * HH * 2;
    __bf16* hB = (__bf16*)w;   w += (size_t)32768 * HH * 2;
    __bf16* hhhu = (__bf16*)w; w += CAP * 1024 * 2;
    __bf16* rh = (__bf16*)w;   w += CAP * 768 * 2;
    __bf16* Wrb = (__bf16*)w;  w += (size_t)768 * 768 * 2;
    __bf16* Whb = (__bf16*)w;  w += (size_t)256 * 768 * 2;
    __bf16* Wzb = (__bf16*)w;  w += (size_t)1024 * 1024 * 2;
    float* bzp = (float*)w;    w += 1024 * 4;

    convert_weights<<<2048, 256, 0, stream>>>(Wr, Wh, Wz, bz, Wrb, Whb, Wzb, bzp);

    for (int l = DEPTH - 1; l >= 0; --l) {
        const size_t M = (size_t)BB << l;
        __bf16* dst = ((DEPTH - 1 - l) & 1) ? hB : hA;
        const __bf16* src = ((DEPTH - 1 - l) & 1) ? hA : hB;  // unused at l=8
        for (size_t r0 = 0; r0 < M; r0 += CAP) {
            const int R = (int)((M - r0 < CAP) ? (M - r0) : CAP);
            build_hhu<<<R / 8, 256, 0, stream>>>(data, Wu, bu, src, hhhu, l, (int)r0);
            if (R >= 16384) {
                gemm256w<EPI_SIGMUL><<<dim3(3, R / 256), 1024, 0, stream>>>(
                    hhhu + 256, 1024, Wrb, br, hhhu + 256, 1024, rh, 768, 768);
            } else {
                gemm_mfma<EPI_SIGMUL><<<dim3(6, R / 128), 256, 0, stream>>>(
                    hhhu + 256, 1024, Wrb, br, hhhu + 256, 1024, rh, 768, 768);
            }
            gemm_mfma<EPI_RELU><<<dim3(2, R / 128), 256, 0, stream>>>(
                rh, 768, Whb, bh, nullptr, 0, hhhu, 1024, 768);
            if (R >= 16384) {
                gemm256w<EPI_COMBINE><<<dim3(4, R / 256), 1024, 0, stream>>>(
                    hhhu, 1024, Wzb, bzp, hhhu, 1024,
                    dst + (size_t)r0 * HH, HH, 1024);
            } else {
                gemm_mfma<EPI_COMBINE><<<dim3(8, R / 128), 256, 0, stream>>>(
                    hhhu, 1024, Wzb, bzp, hhhu, 1024,
                    dst + (size_t)r0 * HH, HH, 1024);
            }
        }
    }
    final_kernel<<<BB, 256, 0, stream>>>(hA, Wp, bp, out);
}

// Round 13
// 1172.511 us; speedup vs baseline: 1.3728x; 1.0112x over previous
//
#include <hip/hip_runtime.h>
#include <math.h>

#define BB 256
#define NN 1023
#define FF 8
#define HH 256
#define DEPTH 9

enum { EPI_NONE = 0, EPI_SIGMUL = 1, EPI_RELU = 2, EPI_COMBINE = 3 };

typedef __bf16 bf16x8_t __attribute__((ext_vector_type(8)));
typedef float f32x4_t __attribute__((ext_vector_type(4)));

__device__ __forceinline__ void stage16(const void* g, void* l) {
    __builtin_amdgcn_global_load_lds(
        (const __attribute__((address_space(1))) void*)g,
        (__attribute__((address_space(3))) void*)l,
        16, 0, 0);
}

__device__ __forceinline__ int xcd_remap(int hw, int nwg) {
    const int xcd = hw & 7, k0 = hw >> 3;
    const int qq = nwg >> 3, rr = nwg & 7;
    return (xcd < rr ? xcd * (qq + 1) : rr * (qq + 1) + (xcd - rr) * qq) + k0;
}

// ======== 256x256 tile, BK=64, 16 waves (64x64 C each), counted vmcnt =======
// K-loop identical to r10-r12. COMBINE epilogue writes children DIRECTLY into
// the parent level's hhhu slots (row gi>>1, col 512 + (gi&1)*256) via the
// dead-LDS bounce panel — this replaces the old build_hhu h-copy entirely.
template <int EPI>
__global__ __launch_bounds__(1024, 4) void gemm256w(
    const __bf16* __restrict__ A, int lda,
    const __bf16* __restrict__ W,       // Nc x K row-major
    const float* __restrict__ bias,
    const __bf16* __restrict__ aux, int ldaux,
    void* __restrict__ Cout, int ldc,
    int r0c,                            // global child-row base of this chunk
    int K)
{
    __shared__ __bf16 lds[2][2][256 * 64];  // 128 KiB
    const int tid = threadIdx.x;
    const int lane = tid & 63;
    const int w = tid >> 6;            // 0..15
    const int wr = w >> 2, wc = w & 3; // per-wave C = 64x64

    const int nwg = gridDim.x * gridDim.y;
    const int hw = blockIdx.y * gridDim.x + blockIdx.x;
    const int wg = xcd_remap(hw, nwg);
    const int bm0 = (wg / gridDim.x) * 256;
    const int bn0 = (wg % gridDim.x) * 256;

    const int srow = tid >> 3;                       // 0..127
    const int scolz = ((tid & 7) ^ (srow & 7)) * 8;  // inv-swizzled col

    f32x4_t acc[4][4];
#pragma unroll
    for (int i = 0; i < 4; ++i)
#pragma unroll
        for (int j = 0; j < 4; ++j) acc[i][j] = (f32x4_t){0.f, 0.f, 0.f, 0.f};

    const int rA = lane & 15;
    const int klane = (lane >> 4) * 8;
    const int rxor = (lane & 7) * 8;
    const int NT = K >> 6;

#define STAGE_T(t, buf)                                                        \
    do {                                                                       \
        const int kk_ = (t) << 6;                                              \
        stage16(A + (size_t)(bm0 + srow) * lda + kk_ + scolz,                  \
                &lds[buf][0][w * 512]);                                        \
        stage16(A + (size_t)(bm0 + 128 + srow) * lda + kk_ + scolz,            \
                &lds[buf][0][8192 + w * 512]);                                 \
        stage16(W + (size_t)(bn0 + srow) * K + kk_ + scolz,                    \
                &lds[buf][1][w * 512]);                                        \
        stage16(W + (size_t)(bn0 + 128 + srow) * K + kk_ + scolz,              \
                &lds[buf][1][8192 + w * 512]);                                 \
    } while (0)
#define LDA_F(As_, i, ks) \
    (*(const bf16x8_t*)&(As_)[(wr * 64 + (i) * 16 + rA) * 64 + (((ks) * 32 + klane) ^ rxor)])
#define LDB_F(Bs_, j, ks) \
    (*(const bf16x8_t*)&(Bs_)[(wc * 64 + (j) * 16 + rA) * 64 + (((ks) * 32 + klane) ^ rxor)])

    STAGE_T(0, 0);
    STAGE_T(1, 1);
    asm volatile("s_waitcnt vmcnt(4)" ::: "memory");
    __builtin_amdgcn_s_barrier();

    for (int t = 0; t < NT; ++t) {
        const int cur = t & 1;
        const __bf16* As = lds[cur][0];
        const __bf16* Bs = lds[cur][1];
        bf16x8_t af[4], bf[4];

#pragma unroll
        for (int j = 0; j < 4; ++j) bf[j] = LDB_F(Bs, j, 0);
#pragma unroll
        for (int i = 0; i < 4; ++i) af[i] = LDA_F(As, i, 0);
#pragma unroll
        for (int i = 0; i < 4; ++i)
#pragma unroll
            for (int j = 0; j < 4; ++j)
                acc[i][j] = __builtin_amdgcn_mfma_f32_16x16x32_bf16(
                    af[i], bf[j], acc[i][j], 0, 0, 0);
#pragma unroll
        for (int j = 0; j < 4; ++j) bf[j] = LDB_F(Bs, j, 1);
#pragma unroll
        for (int i = 0; i < 4; ++i) af[i] = LDA_F(As, i, 1);
#pragma unroll
        for (int i = 0; i < 2; ++i)
#pragma unroll
            for (int j = 0; j < 4; ++j)
                acc[i][j] = __builtin_amdgcn_mfma_f32_16x16x32_bf16(
                    af[i], bf[j], acc[i][j], 0, 0, 0);

        asm volatile("s_waitcnt lgkmcnt(0)" ::: "memory");
        __builtin_amdgcn_s_barrier();
        if (t + 2 < NT) STAGE_T(t + 2, cur);

        __builtin_amdgcn_s_setprio(1);
#pragma unroll
        for (int i = 2; i < 4; ++i)
#pragma unroll
            for (int j = 0; j < 4; ++j)
                acc[i][j] = __builtin_amdgcn_mfma_f32_16x16x32_bf16(
                    af[i], bf[j], acc[i][j], 0, 0, 0);
        __builtin_amdgcn_s_setprio(0);

        if (t + 1 < NT) {
            if (t + 2 < NT) {
                asm volatile("s_waitcnt vmcnt(4)" ::: "memory");
            } else {
                asm volatile("s_waitcnt vmcnt(0)" ::: "memory");
            }
            __builtin_amdgcn_s_barrier();
        }
    }
#undef STAGE_T
#undef LDA_F
#undef LDB_F

    const int hi = lane >> 4;
    const int r = lane & 15;

    if (EPI == EPI_COMBINE) {
        // h -> parent hhhu slots via LDS panel, coalesced 128B bursts.
        __bf16* pan = &lds[0][0][0];  // [256][72]
        const int g0 = bn0 >> 2;
        float bz4[4];
#pragma unroll
        for (int g = 0; g < 4; ++g) bz4[g] = bias[bn0 + wc * 64 + g * 16 + r];
        const int G = g0 + wc * 16 + r;
#pragma unroll
        for (int i = 0; i < 4; ++i) {
#pragma unroll
            for (int reg = 0; reg < 4; ++reg) {
                const int lr = wr * 64 + i * 16 + hi * 4 + reg;
                const int gr = bm0 + lr;
                float z0 = acc[i][0][reg] + bz4[0];
                float z1 = acc[i][1][reg] + bz4[1];
                float z2 = acc[i][2][reg] + bz4[2];
                float z3 = acc[i][3][reg] + bz4[3];
                float mx = fmaxf(fmaxf(z0, z1), fmaxf(z2, z3));
                float e0 = __expf(z0 - mx), e1 = __expf(z1 - mx);
                float e2 = __expf(z2 - mx), e3 = __expf(z3 - mx);
                const __bf16* hrow = aux + (size_t)gr * ldaux + G;
                float hv = (e0 * (float)hrow[0] + e1 * (float)hrow[256] +
                            e2 * (float)hrow[512] + e3 * (float)hrow[768]) /
                           (e0 + e1 + e2 + e3);
                pan[lr * 72 + wc * 16 + r] = (__bf16)hv;
            }
        }
        __syncthreads();
        const int cbase = r0c + bm0;  // 256-aligned child row base
#pragma unroll
        for (int it = 0; it < 2; ++it) {
            const int unit = it * 1024 + tid;
            const int row = unit >> 3;
            const int c8 = (unit & 7) * 8;
            const int crow = cbase + row;
            bf16x8_t vv = *(const bf16x8_t*)&pan[row * 72 + c8];
            *(bf16x8_t*)((__bf16*)Cout + (size_t)(crow >> 1) * 1024 + 512 +
                         (crow & 1) * 256 + g0 + c8) = vv;
        }
    } else if (EPI == EPI_SIGMUL) {
        // rh through LDS panel [256][256]: coalesced flush.
        __bf16* pan = &lds[0][0][0];
        float bv[4];
#pragma unroll
        for (int j = 0; j < 4; ++j) bv[j] = bias[bn0 + wc * 64 + j * 16 + r];
#pragma unroll
        for (int j = 0; j < 4; ++j) {
            const int lc = wc * 64 + j * 16 + r;
            const int gc = bn0 + lc;
#pragma unroll
            for (int i = 0; i < 4; ++i) {
#pragma unroll
                for (int reg = 0; reg < 4; ++reg) {
                    const int lr = wr * 64 + i * 16 + hi * 4 + reg;
                    const int gr = bm0 + lr;
                    float v = acc[i][j][reg] + bv[j];
                    float s = 1.0f / (1.0f + __expf(-v));
                    v = s * (float)aux[(size_t)gr * ldaux + gc];
                    pan[lr * 256 + lc] = (__bf16)v;
                }
            }
        }
        __syncthreads();
#pragma unroll
        for (int it = 0; it < 8; ++it) {
            const int unit = it * 1024 + tid;
            const int row = unit >> 5;
            const int c8 = (unit & 31) * 8;
            bf16x8_t vv = *(const bf16x8_t*)&pan[row * 256 + c8];
            *(bf16x8_t*)((__bf16*)Cout + (size_t)(bm0 + row) * ldc + bn0 + c8) = vv;
        }
    } else {
#pragma unroll
        for (int j = 0; j < 4; ++j) {
            const int gc = bn0 + wc * 64 + j * 16 + r;
            const float bv = bias[gc];
#pragma unroll
            for (int i = 0; i < 4; ++i) {
#pragma unroll
                for (int reg = 0; reg < 4; ++reg) {
                    const int gr = bm0 + wr * 64 + i * 16 + hi * 4 + reg;
                    float v = acc[i][j][reg] + bv;
                    if (EPI == EPI_RELU) v = fmaxf(v, 0.0f);
                    ((__bf16*)Cout)[(size_t)gr * ldc + gc] = (__bf16)v;
                }
            }
        }
    }
}

// ---------------- 128x128-tile kernel (Wh + small levels) -------------------
// COMBINE: topar=1 -> write parent hhhu slots; topar=0 -> compact (ldc).
template <int EPI>
__global__ __launch_bounds__(256) void gemm_mfma(
    const __bf16* __restrict__ A, int lda,
    const __bf16* __restrict__ W,
    const float* __restrict__ bias,
    const __bf16* __restrict__ aux, int ldaux,
    void* __restrict__ Cout, int ldc,
    int r0c, int topar,
    int K)
{
    __shared__ __bf16 As[128 * 32];
    __shared__ __bf16 Bs[128 * 32];
    const int tid = threadIdx.x;
    const int lane = tid & 63;
    const int w = tid >> 6;
    const int wr = w >> 1, wc = w & 1;

    const int nwg = gridDim.x * gridDim.y;
    const int hw = blockIdx.y * gridDim.x + blockIdx.x;
    const int wg = xcd_remap(hw, nwg);
    const int bm0 = (wg / gridDim.x) * 128;
    const int bn0 = (wg % gridDim.x) * 128;

    const int srow = lane >> 2;
    const int scol = (lane & 3) * 8;

    f32x4_t acc[4][4];
#pragma unroll
    for (int i = 0; i < 4; ++i)
#pragma unroll
        for (int j = 0; j < 4; ++j) acc[i][j] = (f32x4_t){0.f, 0.f, 0.f, 0.f};

    const int rA = lane & 15;
    const int kslot = (lane >> 4) * 8;

    for (int kk = 0; kk < K; kk += 32) {
        stage16(A + (size_t)(bm0 + w * 16 + srow) * lda + kk + scol,
                &As[(w * 16) * 32]);
        stage16(A + (size_t)(bm0 + 64 + w * 16 + srow) * lda + kk + scol,
                &As[(64 + w * 16) * 32]);
        stage16(W + (size_t)(bn0 + w * 16 + srow) * K + kk + scol,
                &Bs[(w * 16) * 32]);
        stage16(W + (size_t)(bn0 + 64 + w * 16 + srow) * K + kk + scol,
                &Bs[(64 + w * 16) * 32]);
        __syncthreads();

        bf16x8_t af[4], bfr[4];
#pragma unroll
        for (int i = 0; i < 4; ++i)
            af[i] = *(const bf16x8_t*)&As[(wr * 64 + i * 16 + rA) * 32 + kslot];
#pragma unroll
        for (int j = 0; j < 4; ++j)
            bfr[j] = *(const bf16x8_t*)&Bs[(wc * 64 + j * 16 + rA) * 32 + kslot];
#pragma unroll
        for (int i = 0; i < 4; ++i)
#pragma unroll
            for (int j = 0; j < 4; ++j)
                acc[i][j] = __builtin_amdgcn_mfma_f32_16x16x32_bf16(
                    af[i], bfr[j], acc[i][j], 0, 0, 0);
        __syncthreads();
    }

    if (EPI == EPI_COMBINE) {
        const int r = lane & 15;
        const int G = ((bn0 + wc * 64) >> 2) + r;
        float bz4[4];
#pragma unroll
        for (int g = 0; g < 4; ++g) bz4[g] = bias[bn0 + wc * 64 + g * 16 + r];
#pragma unroll
        for (int i = 0; i < 4; ++i) {
#pragma unroll
            for (int reg = 0; reg < 4; ++reg) {
                const int gr = bm0 + wr * 64 + i * 16 + (lane >> 4) * 4 + reg;
                float z0 = acc[i][0][reg] + bz4[0];
                float z1 = acc[i][1][reg] + bz4[1];
                float z2 = acc[i][2][reg] + bz4[2];
                float z3 = acc[i][3][reg] + bz4[3];
                float mx = fmaxf(fmaxf(z0, z1), fmaxf(z2, z3));
                float e0 = __expf(z0 - mx), e1 = __expf(z1 - mx);
                float e2 = __expf(z2 - mx), e3 = __expf(z3 - mx);
                const __bf16* hrow = aux + (size_t)gr * ldaux + G;
                float hv = (e0 * (float)hrow[0] + e1 * (float)hrow[256] +
                            e2 * (float)hrow[512] + e3 * (float)hrow[768]) /
                           (e0 + e1 + e2 + e3);
                if (topar) {
                    const int crow = r0c + gr;
                    ((__bf16*)Cout)[(size_t)(crow >> 1) * 1024 + 512 +
                                    (crow & 1) * 256 + G] = (__bf16)hv;
                } else {
                    ((__bf16*)Cout)[(size_t)gr * ldc + G] = (__bf16)hv;
                }
            }
        }
    } else {
#pragma unroll
        for (int j = 0; j < 4; ++j) {
            const int gc = bn0 + wc * 64 + j * 16 + (lane & 15);
            const float bv = bias[gc];
#pragma unroll
            for (int i = 0; i < 4; ++i) {
#pragma unroll
                for (int reg = 0; reg < 4; ++reg) {
                    const int gr = bm0 + wr * 64 + i * 16 + (lane >> 4) * 4 + reg;
                    float v = acc[i][j][reg] + bv;
                    if (EPI == EPI_SIGMUL) {
                        float s = 1.0f / (1.0f + __expf(-v));
                        v = s * (float)aux[(size_t)gr * ldaux + gc];
                        ((__bf16*)Cout)[(size_t)gr * ldc + gc] = (__bf16)v;
                    } else if (EPI == EPI_RELU) {
                        v = fmaxf(v, 0.0f);
                        ((__bf16*)Cout)[(size_t)gr * ldc + gc] = (__bf16)v;
                    } else {
                        ((float*)Cout)[(size_t)gr * ldc + gc] = v;
                    }
                }
            }
        }
    }
}

// Wr/Wh -> bf16; Wz -> bf16 with softmax-group row permutation.
__global__ __launch_bounds__(256) void convert_weights(
    const float* __restrict__ Wr, const float* __restrict__ Wh,
    const float* __restrict__ Wz, const float* __restrict__ bz,
    __bf16* __restrict__ Wrb, __bf16* __restrict__ Whb,
    __bf16* __restrict__ Wzb, float* __restrict__ bzp)
{
    const int NR = 768 * 768, NH2 = 256 * 768, NZ = 1024 * 1024;
    const int idx0 = blockIdx.x * 256 + threadIdx.x;
    for (int i = idx0; i < NR + NH2 + NZ; i += gridDim.x * 256) {
        if (i < NR) Wrb[i] = (__bf16)Wr[i];
        else if (i < NR + NH2) Whb[i - NR] = (__bf16)Wh[i - NR];
        else {
            const int z = i - NR - NH2;
            const int p = z >> 10, k = z & 1023;
            const int o = ((p >> 4) & 3) * 256 + (p >> 6) * 16 + (p & 15);
            Wzb[z] = (__bf16)Wz[(size_t)o * 1024 + k];
        }
    }
    if (idx0 < 1024) {
        const int p = idx0;
        const int o = ((p >> 4) & 3) * 256 + (p >> 6) * 16 + (p & 15);
        bzp[p] = bz[o];
    }
}

// l==8 only: fill hhhu slice rows with [u | h_leaf_l | h_leaf_r].
__global__ __launch_bounds__(256) void build_leaf(
    const float* __restrict__ data, const float* __restrict__ Wu,
    const float* __restrict__ bu, __bf16* __restrict__ slice, int r0)
{
    const int blk = xcd_remap(blockIdx.x, gridDim.x);
    const int row = blk * 8 + (threadIdx.x >> 5);
    const int c0 = (threadIdx.x & 31) * 8;
    const int i = r0 + row;
    const int b = i >> 8;
    const int m = i & 255;

    float wv[8][8];
#pragma unroll
    for (int cc = 0; cc < 8; ++cc) {
        float4 w0 = *(const float4*)&Wu[(c0 + cc) * 8];
        float4 w1 = *(const float4*)&Wu[(c0 + cc) * 8 + 4];
        wv[cc][0] = w0.x; wv[cc][1] = w0.y; wv[cc][2] = w0.z; wv[cc][3] = w0.w;
        wv[cc][4] = w1.x; wv[cc][5] = w1.y; wv[cc][6] = w1.z; wv[cc][7] = w1.w;
    }
    float buv[8];
#pragma unroll
    for (int cc = 0; cc < 8; ++cc) buv[cc] = bu[c0 + cc];

    __bf16* rowp = slice + (size_t)row * 1024;
    {
        const float* dp = data + ((size_t)b * NN + 255 + m) * FF;
        float4 d0 = *(const float4*)dp, d1 = *(const float4*)(dp + 4);
        float dv[8] = {d0.x, d0.y, d0.z, d0.w, d1.x, d1.y, d1.z, d1.w};
        bf16x8_t o;
#pragma unroll
        for (int cc = 0; cc < 8; ++cc) {
            float acc = buv[cc];
#pragma unroll
            for (int f = 0; f < 8; ++f) acc += dv[f] * wv[cc][f];
            o[cc] = (__bf16)acc;
        }
        *(bf16x8_t*)&rowp[256 + c0] = o;
    }
    const float* dl = data + ((size_t)b * NN + 511 + 2 * m) * FF;
#pragma unroll
    for (int side = 0; side < 2; ++side) {
        const float* dp = dl + side * FF;
        float4 d0 = *(const float4*)dp, d1 = *(const float4*)(dp + 4);
        float dv[8] = {d0.x, d0.y, d0.z, d0.w, d1.x, d1.y, d1.z, d1.w};
        bf16x8_t o;
#pragma unroll
        for (int cc = 0; cc < 8; ++cc) {
            float acc = buv[cc];
#pragma unroll
            for (int f = 0; f < 8; ++f) acc += dv[f] * wv[cc][f];
            o[cc] = (__bf16)acc;
        }
        *(bf16x8_t*)&rowp[512 + side * 256 + c0] = o;
    }
}

// l<8: write only the u slot (cols 256..512); h_l/h_r already in place.
__global__ __launch_bounds__(256) void build_u(
    const float* __restrict__ data, const float* __restrict__ Wu,
    const float* __restrict__ bu, __bf16* __restrict__ slice, int l, int r0)
{
    const int n = 1 << l;
    const int blk = xcd_remap(blockIdx.x, gridDim.x);
    const int row = blk * 8 + (threadIdx.x >> 5);
    const int c0 = (threadIdx.x & 31) * 8;
    const int i = r0 + row;
    const int b = i >> l;
    const int m = i & (n - 1);

    float wv[8][8];
#pragma unroll
    for (int cc = 0; cc < 8; ++cc) {
        float4 w0 = *(const float4*)&Wu[(c0 + cc) * 8];
        float4 w1 = *(const float4*)&Wu[(c0 + cc) * 8 + 4];
        wv[cc][0] = w0.x; wv[cc][1] = w0.y; wv[cc][2] = w0.z; wv[cc][3] = w0.w;
        wv[cc][4] = w1.x; wv[cc][5] = w1.y; wv[cc][6] = w1.z; wv[cc][7] = w1.w;
    }
    const float* dp = data + ((size_t)b * NN + (n - 1) + m) * FF;
    float4 d0 = *(const float4*)dp, d1 = *(const float4*)(dp + 4);
    float dv[8] = {d0.x, d0.y, d0.z, d0.w, d1.x, d1.y, d1.z, d1.w};
    bf16x8_t o;
#pragma unroll
    for (int cc = 0; cc < 8; ++cc) {
        float acc = bu[c0 + cc];
#pragma unroll
        for (int f = 0; f < 8; ++f) acc += dv[f] * wv[cc][f];
        o[cc] = (__bf16)acc;
    }
    *(bf16x8_t*)&slice[(size_t)row * 1024 + 256 + c0] = o;
}

__global__ __launch_bounds__(256) void final_kernel(
    const __bf16* __restrict__ hfin, const float* __restrict__ Wp,
    const float* __restrict__ bp, float* __restrict__ out)
{
    const int b = blockIdx.x;
    const int t = threadIdx.x;
    __shared__ float red[256];
    red[t] = (float)hfin[(size_t)b * HH + t] * Wp[t];
    __syncthreads();
    for (int s = 128; s > 0; s >>= 1) {
        if (t < s) red[t] += red[t + s];
        __syncthreads();
    }
    if (t == 0) out[b] = red[0] + bp[0];
}

extern "C" void kernel_launch(void* const* d_in, const int* in_sizes, int n_in,
                              void* d_out, int out_size, void* d_ws, size_t ws_size,
                              hipStream_t stream)
{
    const float* data = (const float*)d_in[0];
    const float* Wu = (const float*)d_in[1];
    const float* bu = (const float*)d_in[2];
    const float* Wr = (const float*)d_in[3];
    const float* br = (const float*)d_in[4];
    const float* Wh = (const float*)d_in[5];
    const float* bh = (const float*)d_in[6];
    const float* Wz = (const float*)d_in[7];
    const float* bz = (const float*)d_in[8];
    const float* Wp = (const float*)d_in[9];
    const float* bp = (const float*)d_in[10];
    float* out = (float*)d_out;

    const size_t CAP = 16384;
    char* w = (char*)d_ws;
    __bf16* hhhuA = (__bf16*)w; w += (size_t)65536 * 1024 * 2;  // 134.2 MB (l even)
    __bf16* hhhuB = (__bf16*)w; w += (size_t)32768 * 1024 * 2;  // 67.1 MB (l odd)
    __bf16* rh = (__bf16*)w;    w += CAP * 768 * 2;             // 25.2 MB
    __bf16* hRoot = (__bf16*)w; w += (size_t)256 * 256 * 2;
    __bf16* Wrb = (__bf16*)w;   w += (size_t)768 * 768 * 2;
    __bf16* Whb = (__bf16*)w;   w += (size_t)256 * 768 * 2;
    __bf16* Wzb = (__bf16*)w;   w += (size_t)1024 * 1024 * 2;
    float* bzp = (float*)w;     w += 1024 * 4;

    convert_weights<<<2048, 256, 0, stream>>>(Wr, Wh, Wz, bz, Wrb, Whb, Wzb, bzp);

    for (int l = DEPTH - 1; l >= 0; --l) {
        const size_t M = (size_t)BB << l;
        __bf16* cur = (l & 1) ? hhhuB : hhhuA;
        __bf16* par = (l == 0) ? hRoot : ((l & 1) ? hhhuA : hhhuB);
        const int topar = (l > 0);
        for (size_t r0 = 0; r0 < M; r0 += CAP) {
            const int R = (int)((M - r0 < CAP) ? (M - r0) : CAP);
            __bf16* slice = cur + (size_t)r0 * 1024;
            if (l == 8)
                build_leaf<<<R / 8, 256, 0, stream>>>(data, Wu, bu, slice, (int)r0);
            else
                build_u<<<R / 8, 256, 0, stream>>>(data, Wu, bu, slice, l, (int)r0);
            if (R >= 16384) {
                gemm256w<EPI_SIGMUL><<<dim3(3, R / 256), 1024, 0, stream>>>(
                    slice + 256, 1024, Wrb, br, slice + 256, 1024, rh, 768, 0, 768);
            } else {
                gemm_mfma<EPI_SIGMUL><<<dim3(6, R / 128), 256, 0, stream>>>(
                    slice + 256, 1024, Wrb, br, slice + 256, 1024, rh, 768, 0, 0, 768);
            }
            gemm_mfma<EPI_RELU><<<dim3(2, R / 128), 256, 0, stream>>>(
                rh, 768, Whb, bh, nullptr, 0, slice, 1024, 0, 0, 768);
            if (R >= 16384) {
                gemm256w<EPI_COMBINE><<<dim3(4, R / 256), 1024, 0, stream>>>(
                    slice, 1024, Wzb, bzp, slice, 1024, par, HH, (int)r0, 1024);
            } else {
                gemm_mfma<EPI_COMBINE><<<dim3(8, R / 128), 256, 0, stream>>>(
                    slice, 1024, Wzb, bzp, slice, 1024, par, HH, (int)r0, topar, 1024);
            }
        }
    }
    final_kernel<<<BB, 256, 0, stream>>>(hRoot, Wp, bp, out);
}